// Round 2
// baseline (1588.749 us; speedup 1.0000x reference)
//
#include <hip/hip_runtime.h>
#include <stdint.h>

#define NN 100000
#define EE 800000
#define DD 64
#define GEMM_BLOCKS 1563   // ceil(100000/64)
#define GATHER_BLOCKS 25000

// ============================ threefry / noise ============================
__device__ __forceinline__ void tf_round(uint32_t& x0, uint32_t& x1, int r) {
  x0 += x1;
  x1 = (x1 << r) | (x1 >> (32 - r));
  x1 ^= x0;
}

// threefry2x32 with key (0, 42) == jax.random.key(42)
__device__ __forceinline__ void threefry_0_42(uint32_t c0, uint32_t c1,
                                              uint32_t& o0, uint32_t& o1) {
  const uint32_t ks0 = 0u, ks1 = 42u, ks2 = 0x1BD11BDAu ^ 42u;
  uint32_t x0 = c0 + ks0, x1 = c1 + ks1;
  tf_round(x0, x1, 13); tf_round(x0, x1, 15); tf_round(x0, x1, 26); tf_round(x0, x1, 6);
  x0 += ks1; x1 += ks2 + 1u;
  tf_round(x0, x1, 17); tf_round(x0, x1, 29); tf_round(x0, x1, 16); tf_round(x0, x1, 24);
  x0 += ks2; x1 += ks0 + 2u;
  tf_round(x0, x1, 13); tf_round(x0, x1, 15); tf_round(x0, x1, 26); tf_round(x0, x1, 6);
  x0 += ks0; x1 += ks1 + 3u;
  tf_round(x0, x1, 17); tf_round(x0, x1, 29); tf_round(x0, x1, 16); tf_round(x0, x1, 24);
  x0 += ks1; x1 += ks2 + 4u;
  tf_round(x0, x1, 13); tf_round(x0, x1, 15); tf_round(x0, x1, 26); tf_round(x0, x1, 6);
  x0 += ks2; x1 += ks0 + 5u;
  o0 = x0; o1 = x1;
}

// XLA f32 erfinv (Giles) — matches lax.erf_inv to ~1 ulp
__device__ __forceinline__ float erfinv_f32(float x) {
  float w = -log1pf(-x * x);
  float ww = w - 2.5f;
  float p1 = 2.81022636e-08f;
  p1 = fmaf(p1, ww, 3.43273939e-07f);
  p1 = fmaf(p1, ww, -3.5233877e-06f);
  p1 = fmaf(p1, ww, -4.39150654e-06f);
  p1 = fmaf(p1, ww, 0.00021858087f);
  p1 = fmaf(p1, ww, -0.00125372503f);
  p1 = fmaf(p1, ww, -0.00417768164f);
  p1 = fmaf(p1, ww, 0.246640727f);
  p1 = fmaf(p1, ww, 1.50140941f);
  float ws = sqrtf(w) - 3.0f;
  float p2 = -0.000200214257f;
  p2 = fmaf(p2, ws, 0.000100950558f);
  p2 = fmaf(p2, ws, 0.00134934322f);
  p2 = fmaf(p2, ws, -0.00367342844f);
  p2 = fmaf(p2, ws, 0.00573950773f);
  p2 = fmaf(p2, ws, -0.0076224613f);
  p2 = fmaf(p2, ws, 0.00943887047f);
  p2 = fmaf(p2, ws, 1.00167406f);
  p2 = fmaf(p2, ws, 2.83297682f);
  float p = (w < 5.0f) ? p1 : p2;
  return p * x;
}

// noise[s][n][d] of jax.random.normal(key(42), (4,100000,64)) * 0.1
// JAX >= 0.4.36 default: jax_threefry_partitionable=True.
// 32-bit draws: counter = 64-bit flat index f -> threefry((0,42), (f>>32, f&0xffffffff)),
// bits = out0 ^ out1. Here f < 2^32 so c0 = 0, c1 = f.
__device__ __forceinline__ float noise_val(int s, int n, int d) {
  uint32_t f = (uint32_t)s * 6400000u + (uint32_t)n * 64u + (uint32_t)d;
  uint32_t o0, o1;
  threefry_0_42(0u, f, o0, o1);
  uint32_t bits = o0 ^ o1;
  float v = __uint_as_float((bits >> 9) | 0x3f800000u) - 1.0f;
  const float LO = -0.99999994f;   // nextafter(-1, 0)
  float u = v * 2.0f + LO;         // (hi-lo) rounds to 2.0f in f32
  u = fmaxf(u, LO);
  return 0.1f * (1.41421356f * erfinv_f32(u));
}

// ============================ mask dtype detection ============================
// mode: 0 = int32 {0,1}, 1 = byte {0,1}, 2 = float32 {0.0,1.0}
__device__ __forceinline__ int mask_at(const void* m, int e, int mode) {
  if (mode == 0) return ((const int*)m)[e] != 0;
  if (mode == 1) return ((const unsigned char*)m)[e] != 0;
  return ((const float*)m)[e] != 0.0f;
}

__global__ void k_detect(const unsigned* mw, int* mode_out) {
  __shared__ int nonbin, nonfloat;
  if (threadIdx.x == 0) { nonbin = 0; nonfloat = 0; }
  __syncthreads();
  int lb = 0, lf = 0;
  for (int i = threadIdx.x; i < 4096; i += 256) {
    unsigned v = mw[i];
    if (v > 1u) lb = 1;
    if (v != 0u && v != 0x3F800000u) lf = 1;
  }
  if (lb) atomicOr(&nonbin, 1);
  if (lf) atomicOr(&nonfloat, 1);
  __syncthreads();
  if (threadIdx.x == 0)
    mode_out[0] = (nonbin == 0) ? 0 : ((nonfloat == 0) ? 2 : 1);
}

// ============================ CSR build ============================
__global__ void k_count(const void* mask, const int* dst, int* cnt, const int* mode_p) {
  int e = blockIdx.x * 256 + threadIdx.x;
  if (e >= EE) return;
  if (mask_at(mask, e, *mode_p)) atomicAdd(&cnt[dst[e]], 1);
}

__global__ void k_scan_a(const int* cnt, int* blockSums) {
  __shared__ int sd[256];
  int t = threadIdx.x;
  int base = blockIdx.x * 1024 + t * 4;
  int s = 0;
  #pragma unroll
  for (int j = 0; j < 4; ++j) {
    int i = base + j;
    if (i < NN) s += cnt[i];
  }
  sd[t] = s;
  __syncthreads();
  for (int off = 128; off > 0; off >>= 1) {
    if (t < off) sd[t] += sd[t + off];
    __syncthreads();
  }
  if (t == 0) blockSums[blockIdx.x] = sd[0];
}

__global__ void k_scan_b(int* blockSums, int nb, int* total_out) {
  __shared__ int sd[128];
  int t = threadIdx.x;
  int v = (t < nb) ? blockSums[t] : 0;
  sd[t] = v;
  __syncthreads();
  for (int off = 1; off < 128; off <<= 1) {
    int x = (t >= off) ? sd[t - off] : 0;
    __syncthreads();
    sd[t] += x;
    __syncthreads();
  }
  if (t < nb) blockSums[t] = sd[t] - v;       // exclusive
  if (t == 0) total_out[0] = sd[127];
}

__global__ void k_scan_c(const int* cnt, const int* blockOffs, int* row_ptr,
                         int* cursor, float* cinv) {
  __shared__ int sd[256];
  int t = threadIdx.x;
  int base = blockIdx.x * 1024 + t * 4;
  int v[4], s = 0;
  #pragma unroll
  for (int j = 0; j < 4; ++j) {
    int i = base + j;
    v[j] = (i < NN) ? cnt[i] : 0;
    s += v[j];
  }
  sd[t] = s;
  __syncthreads();
  for (int off = 1; off < 256; off <<= 1) {
    int x = (t >= off) ? sd[t - off] : 0;
    __syncthreads();
    sd[t] += x;
    __syncthreads();
  }
  int excl = sd[t] - s + blockOffs[blockIdx.x];
  #pragma unroll
  for (int j = 0; j < 4; ++j) {
    int i = base + j;
    if (i < NN) {
      row_ptr[i] = excl;
      cursor[i] = excl;
      cinv[i] = 1.0f / fmaxf((float)v[j], 1.0f);
    }
    excl += v[j];
  }
}

__global__ void k_fill(const void* mask, const int* src, const int* dst,
                       int* cursor, int* col, const int* mode_p) {
  int e = blockIdx.x * 256 + threadIdx.x;
  if (e >= EE) return;
  if (mask_at(mask, e, *mode_p)) {
    int p = atomicAdd(&cursor[dst[e]], 1);
    col[p] = src[e];
  }
}

// ============================ precompute folded matrices ============================
// A1 = WmT @ Wu2, A2 = WmB @ Wu2, C1 = msg_b @ Wu2   (per layer)
__global__ void k_precomp(const float* msg_W, const float* msg_b, const float* upd_W,
                          float* A1, float* A2, float* C1) {
  int l = blockIdx.x, t = threadIdx.x;
  const float* WmT = msg_W + l * 128 * 64;
  const float* WmB = WmT + 64 * 64;
  const float* Wu2 = upd_W + l * 128 * 64 + 64 * 64;
  for (int o = t; o < 4096; o += 256) {
    int a = o >> 6, b = o & 63;
    float a1 = 0.f, a2 = 0.f;
    for (int j = 0; j < 64; ++j) {
      float w2 = Wu2[j * 64 + b];
      a1 = fmaf(WmT[a * 64 + j], w2, a1);
      a2 = fmaf(WmB[a * 64 + j], w2, a2);
    }
    A1[l * 4096 + o] = a1;
    A2[l * 4096 + o] = a2;
  }
  if (t < 64) {
    float acc = 0.f;
    for (int j = 0; j < 64; ++j) acc = fmaf(msg_b[l * 64 + j], Wu2[j * 64 + t], acc);
    C1[l * 64 + t] = acc;
  }
}

// ============================ gather (masked neighbor sum) ============================
__global__ __launch_bounds__(256) void k_gather(const int* __restrict__ row_ptr,
                                                const int* __restrict__ col,
                                                const float* __restrict__ H,
                                                float* __restrict__ S) {
  int n = blockIdx.x * 4 + (threadIdx.x >> 6);
  int lane = threadIdx.x & 63;
  if (n >= NN) return;
  int beg = row_ptr[n], end = row_ptr[n + 1];
  float acc = 0.f;
  for (int e = beg; e < end; ++e) {
    int s = col[e];
    acc += H[(size_t)s * 64 + lane];
  }
  S[(size_t)n * 64 + lane] = acc;
}

// ============================ GEMM core (64x64 tile, 4x4/thread) ============================
// LDS tiles are k-major transposed: lT[k*64 + r]; W is lW[k*64 + c].
template <bool SCALE>
__device__ __forceinline__ void mm_pass(const float* lT, const float* lW,
                                        float (&acc)[4][4], int r0, int c0,
                                        const float g4[4]) {
  #pragma unroll 8
  for (int k = 0; k < 64; ++k) {
    float4 a = *(const float4*)(lT + k * 64 + r0);
    float4 w = *(const float4*)(lW + k * 64 + c0);
    float av[4] = {a.x, a.y, a.z, a.w};
    if (SCALE) {
      av[0] *= g4[0]; av[1] *= g4[1]; av[2] *= g4[2]; av[3] *= g4[3];
    }
    float wv[4] = {w.x, w.y, w.z, w.w};
    #pragma unroll
    for (int i = 0; i < 4; ++i)
      #pragma unroll
      for (int j = 0; j < 4; ++j)
        acc[i][j] = fmaf(av[i], wv[j], acc[i][j]);
  }
}

__device__ __forceinline__ void stage_T(const float* __restrict__ src, int R0,
                                        float* lT, const float* __restrict__ rowscale) {
  int t = threadIdx.x;
  int r = t >> 2, cseg = (t & 3) << 4;
  int gr = R0 + r;
  bool ok = gr < NN;
  float sc = 1.f;
  if (ok && rowscale) sc = rowscale[gr];
  #pragma unroll
  for (int q = 0; q < 4; ++q) {
    float4 v = make_float4(0.f, 0.f, 0.f, 0.f);
    if (ok) v = *(const float4*)(src + (size_t)gr * 64 + cseg + 4 * q);
    int k = cseg + 4 * q;
    lT[(k + 0) * 64 + r] = v.x * sc;
    lT[(k + 1) * 64 + r] = v.y * sc;
    lT[(k + 2) * 64 + r] = v.z * sc;
    lT[(k + 3) * 64 + r] = v.w * sc;
  }
}

__device__ __forceinline__ void load_W(const float* __restrict__ W, float* lW) {
  int t = threadIdx.x;
  #pragma unroll
  for (int q = 0; q < 4; ++q) {
    int idx = (q * 256 + t) * 4;
    *(float4*)(lW + idx) = *(const float4*)(W + idx);
  }
}

// -------- input projection: H = relu((x + noise_i) @ Wi + bi) --------
__global__ __launch_bounds__(256) void k_gemm_input(const float* __restrict__ x,
                                                    const float* __restrict__ Wi,
                                                    const float* __restrict__ bi,
                                                    float* __restrict__ Hout, int inst) {
  __shared__ __align__(16) float lT[4096];
  __shared__ __align__(16) float lW[4096];
  __shared__ float lB[64];
  int t = threadIdx.x;
  int R0 = blockIdx.x * 64;
  {
    int r = t >> 2, cseg = (t & 3) << 4;
    int gr = R0 + r;
    bool ok = gr < NN;
    #pragma unroll
    for (int q = 0; q < 4; ++q) {
      float4 v = make_float4(0.f, 0.f, 0.f, 0.f);
      int k = cseg + 4 * q;
      if (ok) {
        v = *(const float4*)(x + (size_t)gr * 64 + k);
        if (inst > 0) {
          int s = inst - 1;
          v.x += noise_val(s, gr, k + 0);
          v.y += noise_val(s, gr, k + 1);
          v.z += noise_val(s, gr, k + 2);
          v.w += noise_val(s, gr, k + 3);
        }
      }
      lT[(k + 0) * 64 + r] = v.x;
      lT[(k + 1) * 64 + r] = v.y;
      lT[(k + 2) * 64 + r] = v.z;
      lT[(k + 3) * 64 + r] = v.w;
    }
  }
  load_W(Wi, lW);
  if (t < 64) lB[t] = bi[t];
  __syncthreads();
  float acc[4][4] = {};
  int r0 = (t & 15) << 2, c0 = (t >> 4) << 2;
  mm_pass<false>(lT, lW, acc, r0, c0, nullptr);
  #pragma unroll
  for (int ri = 0; ri < 4; ++ri) {
    int gr = R0 + r0 + ri;
    if (gr < NN) {
      float4 o;
      o.x = fmaxf(acc[ri][0] + lB[c0 + 0], 0.f);
      o.y = fmaxf(acc[ri][1] + lB[c0 + 1], 0.f);
      o.z = fmaxf(acc[ri][2] + lB[c0 + 2], 0.f);
      o.w = fmaxf(acc[ri][3] + lB[c0 + 3], 0.f);
      *(float4*)(Hout + (size_t)gr * 64 + c0) = o;
    }
  }
}

// -------- layer update: Hn = relu(H@Wu1 + g*(H@A1) + (cinv*S)@A2 + b0 + g*c1) --------
__global__ __launch_bounds__(256) void k_gemm_layer(const float* __restrict__ Hin,
                                                    const float* __restrict__ S,
                                                    const float* __restrict__ Wu1,
                                                    const float* __restrict__ A1,
                                                    const float* __restrict__ A2,
                                                    const float* __restrict__ b0,
                                                    const float* __restrict__ c1,
                                                    const int* __restrict__ cnt,
                                                    const float* __restrict__ cinv,
                                                    float* __restrict__ Hout) {
  __shared__ __align__(16) float lT[4096];
  __shared__ __align__(16) float lS[4096];
  __shared__ __align__(16) float lW[4096];
  __shared__ float lB[128];
  int t = threadIdx.x;
  int R0 = blockIdx.x * 64;
  stage_T(Hin, R0, lT, nullptr);
  stage_T(S, R0, lS, cinv);
  load_W(Wu1, lW);
  if (t < 64) lB[t] = b0[t];
  else if (t < 128) lB[t] = c1[t - 64];
  __syncthreads();
  int r0 = (t & 15) << 2, c0 = (t >> 4) << 2;
  float g4[4];
  #pragma unroll
  for (int ri = 0; ri < 4; ++ri) {
    int gr = R0 + r0 + ri;
    g4[ri] = (gr < NN && cnt[gr] > 0) ? 1.f : 0.f;
  }
  float acc[4][4] = {};
  mm_pass<false>(lT, lW, acc, r0, c0, g4);
  __syncthreads();
  load_W(A1, lW);
  __syncthreads();
  mm_pass<true>(lT, lW, acc, r0, c0, g4);
  __syncthreads();
  load_W(A2, lW);
  __syncthreads();
  mm_pass<false>(lS, lW, acc, r0, c0, g4);
  #pragma unroll
  for (int ri = 0; ri < 4; ++ri) {
    int gr = R0 + r0 + ri;
    if (gr < NN) {
      float4 o;
      o.x = fmaxf(acc[ri][0] + lB[c0 + 0] + g4[ri] * lB[64 + c0 + 0], 0.f);
      o.y = fmaxf(acc[ri][1] + lB[c0 + 1] + g4[ri] * lB[64 + c0 + 1], 0.f);
      o.z = fmaxf(acc[ri][2] + lB[c0 + 2] + g4[ri] * lB[64 + c0 + 2], 0.f);
      o.w = fmaxf(acc[ri][3] + lB[c0 + 3] + g4[ri] * lB[64 + c0 + 3], 0.f);
      *(float4*)(Hout + (size_t)gr * 64 + c0) = o;
    }
  }
}

// -------- final projection + stats epilogue --------
__global__ __launch_bounds__(256) void k_gemm_final(const float* __restrict__ Hin,
                                                    const float* __restrict__ Wf,
                                                    const float* __restrict__ bfv,
                                                    int inst,
                                                    float* __restrict__ out_causal,
                                                    float* __restrict__ s1,
                                                    float* __restrict__ s2) {
  __shared__ __align__(16) float lT[4096];
  __shared__ __align__(16) float lW[4096];
  __shared__ float lB[64];
  int t = threadIdx.x;
  int R0 = blockIdx.x * 64;
  stage_T(Hin, R0, lT, nullptr);
  load_W(Wf, lW);
  if (t < 64) lB[t] = bfv[t];
  __syncthreads();
  float acc[4][4] = {};
  int r0 = (t & 15) << 2, c0 = (t >> 4) << 2;
  mm_pass<false>(lT, lW, acc, r0, c0, nullptr);
  #pragma unroll
  for (int ri = 0; ri < 4; ++ri) {
    int gr = R0 + r0 + ri;
    if (gr < NN) {
      size_t base = (size_t)gr * 64 + c0;
      float z[4];
      #pragma unroll
      for (int j = 0; j < 4; ++j) z[j] = acc[ri][j] + lB[c0 + j];
      if (inst == 0) {
        *(float4*)(out_causal + base) = make_float4(z[0], z[1], z[2], z[3]);
      } else {
        float4 zc = *(const float4*)(out_causal + base);
        float d0 = z[0] - zc.x, d1 = z[1] - zc.y, d2 = z[2] - zc.z, d3 = z[3] - zc.w;
        float4 a = *(float4*)(s1 + base);
        a.x += d0; a.y += d1; a.z += d2; a.w += d3;
        *(float4*)(s1 + base) = a;
        float4 b = *(float4*)(s2 + base);
        b.x += d0 * d0; b.y += d1 * d1; b.z += d2 * d2; b.w += d3 * d3;
        *(float4*)(s2 + base) = b;
      }
    }
  }
}

// -------- u[n] = max( sum_d (s2 - s1^2/4) / 3 , 1e-6 ) --------
__global__ __launch_bounds__(256) void k_u(const float* __restrict__ s1,
                                           const float* __restrict__ s2,
                                           float* __restrict__ u) {
  int n = blockIdx.x * 4 + (threadIdx.x >> 6);
  int lane = threadIdx.x & 63;
  if (n >= NN) return;
  float a = s1[(size_t)n * 64 + lane];
  float b = s2[(size_t)n * 64 + lane];
  float v = b - a * a * 0.25f;
  for (int off = 32; off > 0; off >>= 1) v += __shfl_down(v, off, 64);
  if (lane == 0) u[n] = fmaxf(v / 3.0f, 1e-6f);
}

// ============================ launch ============================
extern "C" void kernel_launch(void* const* d_in, const int* in_sizes, int n_in,
                              void* d_out, int out_size, void* d_ws, size_t ws_size,
                              hipStream_t stream) {
  const float* x      = (const float*)d_in[0];
  const int*   eidx   = (const int*)d_in[1];
  const void*  mask   = d_in[2];
  const float* Wi     = (const float*)d_in[3];
  const float* bi     = (const float*)d_in[4];
  const float* msg_W  = (const float*)d_in[5];
  const float* msg_b  = (const float*)d_in[6];
  const float* upd_W  = (const float*)d_in[7];
  const float* upd_b  = (const float*)d_in[8];
  const float* Wf     = (const float*)d_in[9];
  const float* bfv    = (const float*)d_in[10];

  const int* src = eidx;
  const int* dst = eidx + EE;

  char* ws = (char*)d_ws;
  size_t off = 0;
  auto alloc = [&](size_t bytes) -> void* {
    void* p = ws + off;
    off += (bytes + 255) & ~(size_t)255;
    return p;
  };
  const size_t HS = (size_t)NN * 64 * sizeof(float);   // 25.6 MB
  float* H0   = (float*)alloc(HS);
  float* H1   = (float*)alloc(HS);
  float* S    = (float*)alloc(HS);
  float* s1   = (float*)alloc(HS);
  float* s2   = (float*)alloc(HS);
  int*   cnt     = (int*)alloc(NN * sizeof(int));
  float* cinv    = (float*)alloc(NN * sizeof(float));
  int*   row_ptr = (int*)alloc((NN + 1) * sizeof(int));
  int*   cursor  = (int*)alloc(NN * sizeof(int));
  int*   col     = (int*)alloc(EE * sizeof(int));
  int*   bsums   = (int*)alloc(128 * sizeof(int));
  int*   mode_p  = (int*)alloc(sizeof(int));
  float* A1      = (float*)alloc(2 * 4096 * sizeof(float));
  float* A2      = (float*)alloc(2 * 4096 * sizeof(float));
  float* C1      = (float*)alloc(2 * 64 * sizeof(float));

  float* out_causal = (float*)d_out;
  float* out_u      = (float*)d_out + (size_t)NN * 64;

  // ---- CSR build ----
  k_detect<<<1, 256, 0, stream>>>((const unsigned*)mask, mode_p);
  hipMemsetAsync(cnt, 0, NN * sizeof(int), stream);
  k_count<<<EE / 256, 256, 0, stream>>>(mask, dst, cnt, mode_p);
  const int SCAN_BLKS = (NN + 1023) / 1024;  // 98
  k_scan_a<<<SCAN_BLKS, 256, 0, stream>>>(cnt, bsums);
  k_scan_b<<<1, 128, 0, stream>>>(bsums, SCAN_BLKS, row_ptr + NN);
  k_scan_c<<<SCAN_BLKS, 256, 0, stream>>>(cnt, bsums, row_ptr, cursor, cinv);
  k_fill<<<EE / 256, 256, 0, stream>>>(mask, src, dst, cursor, col, mode_p);

  // ---- folded matrices ----
  k_precomp<<<2, 256, 0, stream>>>(msg_W, msg_b, upd_W, A1, A2, C1);

  hipMemsetAsync(s1, 0, HS, stream);
  hipMemsetAsync(s2, 0, HS, stream);

  // ---- 5 GNN passes: inst 0 = causal, 1..4 = noisy samples ----
  for (int inst = 0; inst < 5; ++inst) {
    k_gemm_input<<<GEMM_BLOCKS, 256, 0, stream>>>(x, Wi, bi, H0, inst);
    float* Hc = H0;
    float* Hn = H1;
    for (int l = 0; l < 2; ++l) {
      k_gather<<<GATHER_BLOCKS, 256, 0, stream>>>(row_ptr, col, Hc, S);
      k_gemm_layer<<<GEMM_BLOCKS, 256, 0, stream>>>(
          Hc, S, upd_W + (size_t)l * 128 * 64, A1 + (size_t)l * 4096,
          A2 + (size_t)l * 4096, upd_b + (size_t)l * 64, C1 + (size_t)l * 64,
          cnt, cinv, Hn);
      float* tmp = Hc; Hc = Hn; Hn = tmp;
    }
    k_gemm_final<<<GEMM_BLOCKS, 256, 0, stream>>>(Hc, Wf, bfv, inst, out_causal, s1, s2);
  }
  k_u<<<GATHER_BLOCKS, 256, 0, stream>>>(s1, s2, out_u);

  (void)in_sizes; (void)n_in; (void)out_size; (void)ws_size;
}

// Round 3
// 996.712 us; speedup vs baseline: 1.5940x; 1.5940x over previous
//
#include <hip/hip_runtime.h>
#include <stdint.h>

#define NN 100000
#define EE 800000
#define GEMM_BX 1563          // ceil(100000/64)
#define TSTR 68               // padded LDS stride for A-operand tiles (b128-aligned, conflict-light)
#define SLAB ((size_t)NN * 64)

// ============================ threefry / noise ============================
__device__ __forceinline__ void tf_round(uint32_t& x0, uint32_t& x1, int r) {
  x0 += x1;
  x1 = (x1 << r) | (x1 >> (32 - r));
  x1 ^= x0;
}

// threefry2x32 with key (0, 42) == jax.random.key(42)
__device__ __forceinline__ void threefry_0_42(uint32_t c0, uint32_t c1,
                                              uint32_t& o0, uint32_t& o1) {
  const uint32_t ks0 = 0u, ks1 = 42u, ks2 = 0x1BD11BDAu ^ 42u;
  uint32_t x0 = c0 + ks0, x1 = c1 + ks1;
  tf_round(x0, x1, 13); tf_round(x0, x1, 15); tf_round(x0, x1, 26); tf_round(x0, x1, 6);
  x0 += ks1; x1 += ks2 + 1u;
  tf_round(x0, x1, 17); tf_round(x0, x1, 29); tf_round(x0, x1, 16); tf_round(x0, x1, 24);
  x0 += ks2; x1 += ks0 + 2u;
  tf_round(x0, x1, 13); tf_round(x0, x1, 15); tf_round(x0, x1, 26); tf_round(x0, x1, 6);
  x0 += ks0; x1 += ks1 + 3u;
  tf_round(x0, x1, 17); tf_round(x0, x1, 29); tf_round(x0, x1, 16); tf_round(x0, x1, 24);
  x0 += ks1; x1 += ks2 + 4u;
  tf_round(x0, x1, 13); tf_round(x0, x1, 15); tf_round(x0, x1, 26); tf_round(x0, x1, 6);
  x0 += ks2; x1 += ks0 + 5u;
  o0 = x0; o1 = x1;
}

// XLA f32 erfinv (Giles)
__device__ __forceinline__ float erfinv_f32(float x) {
  float w = -log1pf(-x * x);
  float ww = w - 2.5f;
  float p1 = 2.81022636e-08f;
  p1 = fmaf(p1, ww, 3.43273939e-07f);
  p1 = fmaf(p1, ww, -3.5233877e-06f);
  p1 = fmaf(p1, ww, -4.39150654e-06f);
  p1 = fmaf(p1, ww, 0.00021858087f);
  p1 = fmaf(p1, ww, -0.00125372503f);
  p1 = fmaf(p1, ww, -0.00417768164f);
  p1 = fmaf(p1, ww, 0.246640727f);
  p1 = fmaf(p1, ww, 1.50140941f);
  float ws = sqrtf(w) - 3.0f;
  float p2 = -0.000200214257f;
  p2 = fmaf(p2, ws, 0.000100950558f);
  p2 = fmaf(p2, ws, 0.00134934322f);
  p2 = fmaf(p2, ws, -0.00367342844f);
  p2 = fmaf(p2, ws, 0.00573950773f);
  p2 = fmaf(p2, ws, -0.0076224613f);
  p2 = fmaf(p2, ws, 0.00943887047f);
  p2 = fmaf(p2, ws, 1.00167406f);
  p2 = fmaf(p2, ws, 2.83297682f);
  float p = (w < 5.0f) ? p1 : p2;
  return p * x;
}

// jax_threefry_partitionable noise (verified R2): bits = o0^o1 of threefry((0,42),(0,f))
__device__ __forceinline__ float noise_val(int s, int n, int d) {
  uint32_t f = (uint32_t)s * 6400000u + (uint32_t)n * 64u + (uint32_t)d;
  uint32_t o0, o1;
  threefry_0_42(0u, f, o0, o1);
  uint32_t bits = o0 ^ o1;
  float v = __uint_as_float((bits >> 9) | 0x3f800000u) - 1.0f;
  const float LO = -0.99999994f;
  float u = v * 2.0f + LO;
  u = fmaxf(u, LO);
  return 0.1f * (1.41421356f * erfinv_f32(u));
}

// ============================ mask dtype detection ============================
__device__ __forceinline__ int mask_at(const void* m, int e, int mode) {
  if (mode == 0) return ((const int*)m)[e] != 0;
  if (mode == 1) return ((const unsigned char*)m)[e] != 0;
  return ((const float*)m)[e] != 0.0f;
}

__global__ void k_detect(const unsigned* mw, int* mode_out) {
  __shared__ int nonbin, nonfloat;
  if (threadIdx.x == 0) { nonbin = 0; nonfloat = 0; }
  __syncthreads();
  int lb = 0, lf = 0;
  for (int i = threadIdx.x; i < 4096; i += 256) {
    unsigned v = mw[i];
    if (v > 1u) lb = 1;
    if (v != 0u && v != 0x3F800000u) lf = 1;
  }
  if (lb) atomicOr(&nonbin, 1);
  if (lf) atomicOr(&nonfloat, 1);
  __syncthreads();
  if (threadIdx.x == 0)
    mode_out[0] = (nonbin == 0) ? 0 : ((nonfloat == 0) ? 2 : 1);
}

// ============================ CSR build ============================
__global__ void k_count(const void* mask, const int* dst, int* cnt, const int* mode_p) {
  int e = blockIdx.x * 256 + threadIdx.x;
  if (e >= EE) return;
  if (mask_at(mask, e, *mode_p)) atomicAdd(&cnt[dst[e]], 1);
}

__global__ void k_scan_a(const int* cnt, int* blockSums) {
  __shared__ int sd[256];
  int t = threadIdx.x;
  int base = blockIdx.x * 1024 + t * 4;
  int s = 0;
  #pragma unroll
  for (int j = 0; j < 4; ++j) {
    int i = base + j;
    if (i < NN) s += cnt[i];
  }
  sd[t] = s;
  __syncthreads();
  for (int off = 128; off > 0; off >>= 1) {
    if (t < off) sd[t] += sd[t + off];
    __syncthreads();
  }
  if (t == 0) blockSums[blockIdx.x] = sd[0];
}

__global__ void k_scan_b(int* blockSums, int nb, int* total_out) {
  __shared__ int sd[128];
  int t = threadIdx.x;
  int v = (t < nb) ? blockSums[t] : 0;
  sd[t] = v;
  __syncthreads();
  for (int off = 1; off < 128; off <<= 1) {
    int x = (t >= off) ? sd[t - off] : 0;
    __syncthreads();
    sd[t] += x;
    __syncthreads();
  }
  if (t < nb) blockSums[t] = sd[t] - v;
  if (t == 0) total_out[0] = sd[127];
}

__global__ void k_scan_c(const int* cnt, const int* blockOffs, int* row_ptr,
                         int* cursor, float* cinv) {
  __shared__ int sd[256];
  int t = threadIdx.x;
  int base = blockIdx.x * 1024 + t * 4;
  int v[4], s = 0;
  #pragma unroll
  for (int j = 0; j < 4; ++j) {
    int i = base + j;
    v[j] = (i < NN) ? cnt[i] : 0;
    s += v[j];
  }
  sd[t] = s;
  __syncthreads();
  for (int off = 1; off < 256; off <<= 1) {
    int x = (t >= off) ? sd[t - off] : 0;
    __syncthreads();
    sd[t] += x;
    __syncthreads();
  }
  int excl = sd[t] - s + blockOffs[blockIdx.x];
  #pragma unroll
  for (int j = 0; j < 4; ++j) {
    int i = base + j;
    if (i < NN) {
      row_ptr[i] = excl;
      cursor[i] = excl;
      cinv[i] = 1.0f / fmaxf((float)v[j], 1.0f);
    }
    excl += v[j];
  }
}

__global__ void k_fill(const void* mask, const int* src, const int* dst,
                       int* cursor, int* col, const int* mode_p) {
  int e = blockIdx.x * 256 + threadIdx.x;
  if (e >= EE) return;
  if (mask_at(mask, e, *mode_p)) {
    int p = atomicAdd(&cursor[dst[e]], 1);
    col[p] = src[e];
  }
}

// ============================ folded weights ============================
// A1 = WmT @ Wu2, A2 = WmB @ Wu2, C1 = msg_b @ Wu2   (per layer)
__global__ void k_precomp(const float* msg_W, const float* msg_b, const float* upd_W,
                          float* A1, float* A2, float* C1) {
  int l = blockIdx.x, t = threadIdx.x;
  const float* WmT = msg_W + l * 128 * 64;
  const float* WmB = WmT + 64 * 64;
  const float* Wu2 = upd_W + l * 128 * 64 + 64 * 64;
  for (int o = t; o < 4096; o += 256) {
    int a = o >> 6, b = o & 63;
    float a1 = 0.f, a2 = 0.f;
    for (int j = 0; j < 64; ++j) {
      float w2 = Wu2[j * 64 + b];
      a1 = fmaf(WmT[a * 64 + j], w2, a1);
      a2 = fmaf(WmB[a * 64 + j], w2, a2);
    }
    A1[l * 4096 + o] = a1;
    A2[l * 4096 + o] = a2;
  }
  if (t < 64) {
    float acc = 0.f;
    for (int j = 0; j < 64; ++j) acc = fmaf(msg_b[l * 64 + j], Wu2[j * 64 + t], acc);
    C1[l * 64 + t] = acc;
  }
}

// ============================ GEMM micro-kernel ============================
template <bool SCALE>
__device__ __forceinline__ void mm_pass(const float* lA, const float* lW,
                                        float (&acc)[4][4], int r0, int c0,
                                        const float g4[4]) {
  #pragma unroll 8
  for (int k = 0; k < 64; ++k) {
    float4 a = *(const float4*)(lA + k * TSTR + r0);
    float4 w = *(const float4*)(lW + k * 64 + c0);
    float av[4] = {a.x, a.y, a.z, a.w};
    if (SCALE) {
      av[0] *= g4[0]; av[1] *= g4[1]; av[2] *= g4[2]; av[3] *= g4[3];
    }
    float wv[4] = {w.x, w.y, w.z, w.w};
    #pragma unroll
    for (int i = 0; i < 4; ++i)
      #pragma unroll
      for (int j = 0; j < 4; ++j)
        acc[i][j] = fmaf(av[i], wv[j], acc[i][j]);
  }
}

__device__ __forceinline__ void stage_T(const float* __restrict__ src, int R0, float* lT) {
  int t = threadIdx.x;
  int r = t >> 2, cseg = (t & 3) << 4;
  int gr = R0 + r;
  bool ok = gr < NN;
  #pragma unroll
  for (int q = 0; q < 4; ++q) {
    float4 v = make_float4(0.f, 0.f, 0.f, 0.f);
    if (ok) v = *(const float4*)(src + (size_t)gr * 64 + cseg + 4 * q);
    int k = cseg + 4 * q;
    lT[(k + 0) * TSTR + r] = v.x;
    lT[(k + 1) * TSTR + r] = v.y;
    lT[(k + 2) * TSTR + r] = v.z;
    lT[(k + 3) * TSTR + r] = v.w;
  }
}

__device__ __forceinline__ void load_W(const float* __restrict__ W, float* lW) {
  int t = threadIdx.x;
  #pragma unroll
  for (int q = 0; q < 4; ++q) {
    int idx = (q * 256 + t) * 4;
    *(float4*)(lW + idx) = *(const float4*)(W + idx);
  }
}

// -------- input projection: H[inst] = relu((x + noise_inst) @ Wi + bi) --------
__global__ __launch_bounds__(256) void k_input(const float* __restrict__ x,
                                               const float* __restrict__ Wi,
                                               const float* __restrict__ bi,
                                               float* __restrict__ Hbase, size_t hStride,
                                               int instBase) {
  __shared__ __align__(16) float lT[64 * TSTR];
  __shared__ __align__(16) float lW[4096];
  __shared__ float lB[64];
  int t = threadIdx.x;
  int R0 = blockIdx.x * 64;
  int inst = instBase + blockIdx.y;
  float* Hout = Hbase + (size_t)blockIdx.y * hStride;
  {
    int r = t >> 2, cseg = (t & 3) << 4;
    int gr = R0 + r;
    bool ok = gr < NN;
    #pragma unroll
    for (int q = 0; q < 4; ++q) {
      float4 v = make_float4(0.f, 0.f, 0.f, 0.f);
      int k = cseg + 4 * q;
      if (ok) {
        v = *(const float4*)(x + (size_t)gr * 64 + k);
        if (inst > 0) {
          int s = inst - 1;
          v.x += noise_val(s, gr, k + 0);
          v.y += noise_val(s, gr, k + 1);
          v.z += noise_val(s, gr, k + 2);
          v.w += noise_val(s, gr, k + 3);
        }
      }
      lT[(k + 0) * TSTR + r] = v.x;
      lT[(k + 1) * TSTR + r] = v.y;
      lT[(k + 2) * TSTR + r] = v.z;
      lT[(k + 3) * TSTR + r] = v.w;
    }
  }
  load_W(Wi, lW);
  if (t < 64) lB[t] = bi[t];
  __syncthreads();
  float acc[4][4] = {};
  int r0 = (t & 15) << 2, c0 = (t >> 4) << 2;
  mm_pass<false>(lT, lW, acc, r0, c0, nullptr);
  #pragma unroll
  for (int ri = 0; ri < 4; ++ri) {
    int gr = R0 + r0 + ri;
    if (gr < NN) {
      float4 o;
      o.x = fmaxf(acc[ri][0] + lB[c0 + 0], 0.f);
      o.y = fmaxf(acc[ri][1] + lB[c0 + 1], 0.f);
      o.z = fmaxf(acc[ri][2] + lB[c0 + 2], 0.f);
      o.w = fmaxf(acc[ri][3] + lB[c0 + 3], 0.f);
      *(float4*)(Hout + (size_t)gr * 64 + c0) = o;
    }
  }
}

// -------- fused gather + layer update --------
// Hn = relu(H@Wu1 + g*(H@A1) + (cinv*gatherSum(H))@A2 + b0 + g*c1)
__global__ __launch_bounds__(256) void k_layer(const float* __restrict__ HinB, size_t hinStride,
                                               float* __restrict__ HoutB, size_t houtStride,
                                               const int* __restrict__ row_ptr,
                                               const int* __restrict__ col,
                                               const int* __restrict__ cnt,
                                               const float* __restrict__ cinv,
                                               const float* __restrict__ Wu1,
                                               const float* __restrict__ A1,
                                               const float* __restrict__ A2,
                                               const float* __restrict__ b0,
                                               const float* __restrict__ c1) {
  __shared__ __align__(16) float lT[64 * TSTR];
  __shared__ __align__(16) float lS[64 * TSTR];
  __shared__ __align__(16) float lW[4096];
  __shared__ float lB[128];
  int t = threadIdx.x;
  int R0 = blockIdx.x * 64;
  const float* Hin = HinB + (size_t)blockIdx.y * hinStride;
  float* Hout = HoutB + (size_t)blockIdx.y * houtStride;

  stage_T(Hin, R0, lT);
  load_W(Wu1, lW);
  if (t < 64) lB[t] = b0[t];
  else if (t < 128) lB[t] = c1[t - 64];

  // gather: 4 rows in flight per wave (16 lanes x float4 each), 4 batches
  {
    int w = t >> 6;
    int sub = (t >> 4) & 3;
    int f0 = (t & 15) << 2;
    #pragma unroll
    for (int b = 0; b < 4; ++b) {
      int r = w * 16 + b * 4 + sub;
      int n = R0 + r;
      float4 acc = make_float4(0.f, 0.f, 0.f, 0.f);
      if (n < NN) {
        int e = row_ptr[n], end = row_ptr[n + 1];
        for (; e + 4 <= end; e += 4) {
          int s0 = col[e], s1i = col[e + 1], s2i = col[e + 2], s3i = col[e + 3];
          float4 v0 = *(const float4*)(Hin + (size_t)s0 * 64 + f0);
          float4 v1 = *(const float4*)(Hin + (size_t)s1i * 64 + f0);
          float4 v2 = *(const float4*)(Hin + (size_t)s2i * 64 + f0);
          float4 v3 = *(const float4*)(Hin + (size_t)s3i * 64 + f0);
          acc.x += (v0.x + v1.x) + (v2.x + v3.x);
          acc.y += (v0.y + v1.y) + (v2.y + v3.y);
          acc.z += (v0.z + v1.z) + (v2.z + v3.z);
          acc.w += (v0.w + v1.w) + (v2.w + v3.w);
        }
        for (; e < end; ++e) {
          float4 v0 = *(const float4*)(Hin + (size_t)col[e] * 64 + f0);
          acc.x += v0.x; acc.y += v0.y; acc.z += v0.z; acc.w += v0.w;
        }
        float ci = cinv[n];
        acc.x *= ci; acc.y *= ci; acc.z *= ci; acc.w *= ci;
      }
      lS[(f0 + 0) * TSTR + r] = acc.x;
      lS[(f0 + 1) * TSTR + r] = acc.y;
      lS[(f0 + 2) * TSTR + r] = acc.z;
      lS[(f0 + 3) * TSTR + r] = acc.w;
    }
  }
  __syncthreads();

  int r0 = (t & 15) << 2, c0 = (t >> 4) << 2;
  float g4[4];
  #pragma unroll
  for (int ri = 0; ri < 4; ++ri) {
    int gr = R0 + r0 + ri;
    g4[ri] = (gr < NN && cnt[gr] > 0) ? 1.f : 0.f;
  }
  float acc[4][4] = {};
  mm_pass<false>(lT, lW, acc, r0, c0, g4);
  __syncthreads();
  load_W(A1, lW);
  __syncthreads();
  mm_pass<true>(lT, lW, acc, r0, c0, g4);
  __syncthreads();
  load_W(A2, lW);
  __syncthreads();
  mm_pass<false>(lS, lW, acc, r0, c0, g4);
  #pragma unroll
  for (int ri = 0; ri < 4; ++ri) {
    int gr = R0 + r0 + ri;
    if (gr < NN) {
      float4 o;
      o.x = fmaxf(acc[ri][0] + lB[c0 + 0] + g4[ri] * lB[64 + c0 + 0], 0.f);
      o.y = fmaxf(acc[ri][1] + lB[c0 + 1] + g4[ri] * lB[64 + c0 + 1], 0.f);
      o.z = fmaxf(acc[ri][2] + lB[c0 + 2] + g4[ri] * lB[64 + c0 + 2], 0.f);
      o.w = fmaxf(acc[ri][3] + lB[c0 + 3] + g4[ri] * lB[64 + c0 + 3], 0.f);
      *(float4*)(Hout + (size_t)gr * 64 + c0) = o;
    }
  }
}

// -------- final projection --------
// inst 0 -> out_causal; inst>=1: mode 0 -> write z slab; mode 1 -> s1 += z, s2 += z^2
__global__ __launch_bounds__(256) void k_final(const float* __restrict__ HinB, size_t hinStride,
                                               const float* __restrict__ Wf,
                                               const float* __restrict__ bfv,
                                               float* __restrict__ outCausal,
                                               float* __restrict__ Zbase,
                                               float* __restrict__ s1,
                                               float* __restrict__ s2,
                                               int instBase, int mode) {
  __shared__ __align__(16) float lT[64 * TSTR];
  __shared__ __align__(16) float lW[4096];
  __shared__ float lB[64];
  int t = threadIdx.x;
  int R0 = blockIdx.x * 64;
  int inst = instBase + blockIdx.y;
  const float* Hin = HinB + (size_t)blockIdx.y * hinStride;
  stage_T(Hin, R0, lT);
  load_W(Wf, lW);
  if (t < 64) lB[t] = bfv[t];
  __syncthreads();
  float acc[4][4] = {};
  int r0 = (t & 15) << 2, c0 = (t >> 4) << 2;
  mm_pass<false>(lT, lW, acc, r0, c0, nullptr);
  float* zdst = (inst == 0) ? outCausal : (Zbase + (size_t)(inst - 1) * SLAB);
  #pragma unroll
  for (int ri = 0; ri < 4; ++ri) {
    int gr = R0 + r0 + ri;
    if (gr < NN) {
      size_t base = (size_t)gr * 64 + c0;
      float z[4];
      #pragma unroll
      for (int j = 0; j < 4; ++j) z[j] = acc[ri][j] + lB[c0 + j];
      if (inst == 0 || mode == 0) {
        *(float4*)(zdst + base) = make_float4(z[0], z[1], z[2], z[3]);
      } else {
        float4 a = *(float4*)(s1 + base);
        a.x += z[0]; a.y += z[1]; a.z += z[2]; a.w += z[3];
        *(float4*)(s1 + base) = a;
        float4 b = *(float4*)(s2 + base);
        b.x += z[0] * z[0]; b.y += z[1] * z[1]; b.z += z[2] * z[2]; b.w += z[3] * z[3];
        *(float4*)(s2 + base) = b;
      }
    }
  }
}

// -------- u from 4 z-sample slabs (batched path) --------
__global__ __launch_bounds__(256) void k_u_bat(const float* __restrict__ Z,
                                               float* __restrict__ u) {
  int n = blockIdx.x * 4 + (threadIdx.x >> 6);
  int lane = threadIdx.x & 63;
  if (n >= NN) return;
  size_t base = (size_t)n * 64 + lane;
  float z0 = Z[base];
  float z1 = Z[SLAB + base];
  float z2 = Z[2 * SLAB + base];
  float z3 = Z[3 * SLAB + base];
  float m = 0.25f * (z0 + z1 + z2 + z3);
  float d0 = z0 - m, d1 = z1 - m, d2 = z2 - m, d3 = z3 - m;
  float v = d0 * d0 + d1 * d1 + d2 * d2 + d3 * d3;
  for (int off = 32; off > 0; off >>= 1) v += __shfl_down(v, off, 64);
  if (lane == 0) u[n] = fmaxf(v * (1.0f / 3.0f), 1e-6f);
}

// -------- u from s1/s2 (sequential fallback path) --------
__global__ __launch_bounds__(256) void k_u_seq(const float* __restrict__ s1,
                                               const float* __restrict__ s2,
                                               float* __restrict__ u) {
  int n = blockIdx.x * 4 + (threadIdx.x >> 6);
  int lane = threadIdx.x & 63;
  if (n >= NN) return;
  float a = s1[(size_t)n * 64 + lane];
  float b = s2[(size_t)n * 64 + lane];
  float v = b - a * a * 0.25f;
  for (int off = 32; off > 0; off >>= 1) v += __shfl_down(v, off, 64);
  if (lane == 0) u[n] = fmaxf(v * (1.0f / 3.0f), 1e-6f);
}

// ============================ launch ============================
extern "C" void kernel_launch(void* const* d_in, const int* in_sizes, int n_in,
                              void* d_out, int out_size, void* d_ws, size_t ws_size,
                              hipStream_t stream) {
  const float* x      = (const float*)d_in[0];
  const int*   eidx   = (const int*)d_in[1];
  const void*  mask   = d_in[2];
  const float* Wi     = (const float*)d_in[3];
  const float* bi     = (const float*)d_in[4];
  const float* msg_W  = (const float*)d_in[5];
  const float* msg_b  = (const float*)d_in[6];
  const float* upd_W  = (const float*)d_in[7];
  const float* upd_b  = (const float*)d_in[8];
  const float* Wf     = (const float*)d_in[9];
  const float* bfv    = (const float*)d_in[10];

  const int* src = eidx;
  const int* dst = eidx + EE;

  char* ws = (char*)d_ws;
  size_t off = 0;
  auto alloc = [&](size_t bytes) -> void* {
    void* p = ws + off;
    off += (bytes + 255) & ~(size_t)255;
    return p;
  };

  // common small buffers
  int*   cnt     = (int*)alloc(NN * sizeof(int));
  float* cinv    = (float*)alloc(NN * sizeof(float));
  int*   row_ptr = (int*)alloc((NN + 1) * sizeof(int));
  int*   cursor  = (int*)alloc(NN * sizeof(int));
  int*   col     = (int*)alloc(EE * sizeof(int));
  int*   bsums   = (int*)alloc(128 * sizeof(int));
  int*   mode_p  = (int*)alloc(sizeof(int));
  float* A1      = (float*)alloc(2 * 4096 * sizeof(float));
  float* A2      = (float*)alloc(2 * 4096 * sizeof(float));
  float* C1      = (float*)alloc(2 * 64 * sizeof(float));

  const size_t HS = SLAB * sizeof(float);   // 25.6 MB
  bool batched = (ws_size >= off + 10 * HS + (1 << 20));

  float* out_causal = (float*)d_out;
  float* out_u      = (float*)d_out + SLAB;

  // ---- CSR build ----
  k_detect<<<1, 256, 0, stream>>>((const unsigned*)mask, mode_p);
  hipMemsetAsync(cnt, 0, NN * sizeof(int), stream);
  k_count<<<EE / 256, 256, 0, stream>>>(mask, dst, cnt, mode_p);
  const int SCAN_BLKS = (NN + 1023) / 1024;  // 98
  k_scan_a<<<SCAN_BLKS, 256, 0, stream>>>(cnt, bsums);
  k_scan_b<<<1, 128, 0, stream>>>(bsums, SCAN_BLKS, row_ptr + NN);
  k_scan_c<<<SCAN_BLKS, 256, 0, stream>>>(cnt, bsums, row_ptr, cursor, cinv);
  k_fill<<<EE / 256, 256, 0, stream>>>(mask, src, dst, cursor, col, mode_p);
  k_precomp<<<2, 256, 0, stream>>>(msg_W, msg_b, upd_W, A1, A2, C1);

  if (batched) {
    float* H0 = (float*)alloc(5 * HS);
    float* H1 = (float*)alloc(5 * HS);   // doubles as Z after L1
    dim3 g5(GEMM_BX, 5);
    k_input<<<g5, 256, 0, stream>>>(x, Wi, bi, H0, SLAB, 0);
    k_layer<<<g5, 256, 0, stream>>>(H0, SLAB, H1, SLAB, row_ptr, col, cnt, cinv,
                                    upd_W + 0 * 128 * 64, A1 + 0, A2 + 0,
                                    upd_b + 0, C1 + 0);
    k_layer<<<g5, 256, 0, stream>>>(H1, SLAB, H0, SLAB, row_ptr, col, cnt, cinv,
                                    upd_W + (size_t)128 * 64, A1 + 4096, A2 + 4096,
                                    upd_b + 64, C1 + 64);
    // final: inst0 -> out_causal; inst i>=1 -> H1 slab (i-1)  (H1 is dead now)
    k_final<<<g5, 256, 0, stream>>>(H0, SLAB, Wf, bfv, out_causal, H1,
                                    nullptr, nullptr, 0, 0);
    k_u_bat<<<NN / 4, 256, 0, stream>>>(H1, out_u);
  } else {
    float* A_  = (float*)alloc(HS);
    float* B_  = (float*)alloc(HS);
    float* s1  = (float*)alloc(HS);
    float* s2  = (float*)alloc(HS);
    hipMemsetAsync(s1, 0, HS, stream);
    hipMemsetAsync(s2, 0, HS, stream);
    dim3 g1(GEMM_BX, 1);
    for (int inst = 0; inst < 5; ++inst) {
      k_input<<<g1, 256, 0, stream>>>(x, Wi, bi, A_, 0, inst);
      k_layer<<<g1, 256, 0, stream>>>(A_, 0, B_, 0, row_ptr, col, cnt, cinv,
                                      upd_W + 0 * 128 * 64, A1 + 0, A2 + 0,
                                      upd_b + 0, C1 + 0);
      k_layer<<<g1, 256, 0, stream>>>(B_, 0, A_, 0, row_ptr, col, cnt, cinv,
                                      upd_W + (size_t)128 * 64, A1 + 4096, A2 + 4096,
                                      upd_b + 64, C1 + 64);
      k_final<<<g1, 256, 0, stream>>>(A_, 0, Wf, bfv, out_causal, nullptr,
                                      s1, s2, inst, 1);
    }
    k_u_seq<<<NN / 4, 256, 0, stream>>>(s1, s2, out_u);
  }

  (void)in_sizes; (void)n_in; (void)out_size;
}

// Round 4
// 664.278 us; speedup vs baseline: 2.3917x; 1.5004x over previous
//
#include <hip/hip_runtime.h>
#include <stdint.h>

#define NN 100000
#define EE 800000
#define GEMM_BX 1563          // ceil(100000/64)
#define WSTR 72               // padded bf16 LDS row stride (144 B: 2-way bank aliasing = free)
#define SLAB ((size_t)NN * 64)

typedef unsigned short u16;
typedef __attribute__((ext_vector_type(8))) short bf16x8;   // 8 bf16 = 4 VGPRs
typedef __attribute__((ext_vector_type(4))) float f32x4;

// f32 -> bf16 RNE
__device__ __forceinline__ uint32_t f2bf(float f) {
  uint32_t u = __float_as_uint(f);
  return (u + 0x7fffu + ((u >> 16) & 1u)) >> 16;
}

// ============================ threefry / noise ============================
__device__ __forceinline__ void tf_round(uint32_t& x0, uint32_t& x1, int r) {
  x0 += x1;
  x1 = (x1 << r) | (x1 >> (32 - r));
  x1 ^= x0;
}

// threefry2x32 with key (0, 42) == jax.random.key(42)
__device__ __forceinline__ void threefry_0_42(uint32_t c0, uint32_t c1,
                                              uint32_t& o0, uint32_t& o1) {
  const uint32_t ks0 = 0u, ks1 = 42u, ks2 = 0x1BD11BDAu ^ 42u;
  uint32_t x0 = c0 + ks0, x1 = c1 + ks1;
  tf_round(x0, x1, 13); tf_round(x0, x1, 15); tf_round(x0, x1, 26); tf_round(x0, x1, 6);
  x0 += ks1; x1 += ks2 + 1u;
  tf_round(x0, x1, 17); tf_round(x0, x1, 29); tf_round(x0, x1, 16); tf_round(x0, x1, 24);
  x0 += ks2; x1 += ks0 + 2u;
  tf_round(x0, x1, 13); tf_round(x0, x1, 15); tf_round(x0, x1, 26); tf_round(x0, x1, 6);
  x0 += ks0; x1 += ks1 + 3u;
  tf_round(x0, x1, 17); tf_round(x0, x1, 29); tf_round(x0, x1, 16); tf_round(x0, x1, 24);
  x0 += ks1; x1 += ks2 + 4u;
  tf_round(x0, x1, 13); tf_round(x0, x1, 15); tf_round(x0, x1, 26); tf_round(x0, x1, 6);
  x0 += ks2; x1 += ks0 + 5u;
  o0 = x0; o1 = x1;
}

// XLA f32 erfinv (Giles)
__device__ __forceinline__ float erfinv_f32(float x) {
  float w = -log1pf(-x * x);
  float ww = w - 2.5f;
  float p1 = 2.81022636e-08f;
  p1 = fmaf(p1, ww, 3.43273939e-07f);
  p1 = fmaf(p1, ww, -3.5233877e-06f);
  p1 = fmaf(p1, ww, -4.39150654e-06f);
  p1 = fmaf(p1, ww, 0.00021858087f);
  p1 = fmaf(p1, ww, -0.00125372503f);
  p1 = fmaf(p1, ww, -0.00417768164f);
  p1 = fmaf(p1, ww, 0.246640727f);
  p1 = fmaf(p1, ww, 1.50140941f);
  float ws = sqrtf(w) - 3.0f;
  float p2 = -0.000200214257f;
  p2 = fmaf(p2, ws, 0.000100950558f);
  p2 = fmaf(p2, ws, 0.00134934322f);
  p2 = fmaf(p2, ws, -0.00367342844f);
  p2 = fmaf(p2, ws, 0.00573950773f);
  p2 = fmaf(p2, ws, -0.0076224613f);
  p2 = fmaf(p2, ws, 0.00943887047f);
  p2 = fmaf(p2, ws, 1.00167406f);
  p2 = fmaf(p2, ws, 2.83297682f);
  float p = (w < 5.0f) ? p1 : p2;
  return p * x;
}

// jax_threefry_partitionable noise (verified R2): bits = o0^o1 of threefry((0,42),(0,f))
__device__ __forceinline__ float noise_val(int s, int n, int d) {
  uint32_t f = (uint32_t)s * 6400000u + (uint32_t)n * 64u + (uint32_t)d;
  uint32_t o0, o1;
  threefry_0_42(0u, f, o0, o1);
  uint32_t bits = o0 ^ o1;
  float v = __uint_as_float((bits >> 9) | 0x3f800000u) - 1.0f;
  const float LO = -0.99999994f;
  float u = v * 2.0f + LO;
  u = fmaxf(u, LO);
  return 0.1f * (1.41421356f * erfinv_f32(u));
}

// ============================ mask dtype detection ============================
__device__ __forceinline__ int mask_at(const void* m, int e, int mode) {
  if (mode == 0) return ((const int*)m)[e] != 0;
  if (mode == 1) return ((const unsigned char*)m)[e] != 0;
  return ((const float*)m)[e] != 0.0f;
}

__global__ void k_detect(const unsigned* mw, int* mode_out) {
  __shared__ int nonbin, nonfloat;
  if (threadIdx.x == 0) { nonbin = 0; nonfloat = 0; }
  __syncthreads();
  int lb = 0, lf = 0;
  for (int i = threadIdx.x; i < 4096; i += 256) {
    unsigned v = mw[i];
    if (v > 1u) lb = 1;
    if (v != 0u && v != 0x3F800000u) lf = 1;
  }
  if (lb) atomicOr(&nonbin, 1);
  if (lf) atomicOr(&nonfloat, 1);
  __syncthreads();
  if (threadIdx.x == 0)
    mode_out[0] = (nonbin == 0) ? 0 : ((nonfloat == 0) ? 2 : 1);
}

// ============================ CSR build ============================
__global__ void k_count(const void* mask, const int* dst, int* cnt, const int* mode_p) {
  int e = blockIdx.x * 256 + threadIdx.x;
  if (e >= EE) return;
  if (mask_at(mask, e, *mode_p)) atomicAdd(&cnt[dst[e]], 1);
}

__global__ void k_scan_a(const int* cnt, int* blockSums) {
  __shared__ int sd[256];
  int t = threadIdx.x;
  int base = blockIdx.x * 1024 + t * 4;
  int s = 0;
  #pragma unroll
  for (int j = 0; j < 4; ++j) {
    int i = base + j;
    if (i < NN) s += cnt[i];
  }
  sd[t] = s;
  __syncthreads();
  for (int off = 128; off > 0; off >>= 1) {
    if (t < off) sd[t] += sd[t + off];
    __syncthreads();
  }
  if (t == 0) blockSums[blockIdx.x] = sd[0];
}

__global__ void k_scan_b(int* blockSums, int nb, int* total_out) {
  __shared__ int sd[128];
  int t = threadIdx.x;
  int v = (t < nb) ? blockSums[t] : 0;
  sd[t] = v;
  __syncthreads();
  for (int off = 1; off < 128; off <<= 1) {
    int x = (t >= off) ? sd[t - off] : 0;
    __syncthreads();
    sd[t] += x;
    __syncthreads();
  }
  if (t < nb) blockSums[t] = sd[t] - v;
  if (t == 0) total_out[0] = sd[127];
}

__global__ void k_scan_c(const int* cnt, const int* blockOffs, int* row_ptr,
                         int* cursor, float* cinv) {
  __shared__ int sd[256];
  int t = threadIdx.x;
  int base = blockIdx.x * 1024 + t * 4;
  int v[4], s = 0;
  #pragma unroll
  for (int j = 0; j < 4; ++j) {
    int i = base + j;
    v[j] = (i < NN) ? cnt[i] : 0;
    s += v[j];
  }
  sd[t] = s;
  __syncthreads();
  for (int off = 1; off < 256; off <<= 1) {
    int x = (t >= off) ? sd[t - off] : 0;
    __syncthreads();
    sd[t] += x;
    __syncthreads();
  }
  int excl = sd[t] - s + blockOffs[blockIdx.x];
  #pragma unroll
  for (int j = 0; j < 4; ++j) {
    int i = base + j;
    if (i < NN) {
      row_ptr[i] = excl;
      cursor[i] = excl;
      cinv[i] = 1.0f / fmaxf((float)v[j], 1.0f);
    }
    excl += v[j];
  }
}

__global__ void k_fill(const void* mask, const int* src, const int* dst,
                       int* cursor, int* col, const int* mode_p) {
  int e = blockIdx.x * 256 + threadIdx.x;
  if (e >= EE) return;
  if (mask_at(mask, e, *mode_p)) {
    int p = atomicAdd(&cursor[dst[e]], 1);
    col[p] = src[e];
  }
}

// ============================ folded / transposed weights (bf16) ============================
// Per layer: A1 = WmT@Wu2, A2 = WmB@Wu2, C1 = msg_b@Wu2. All weight matrices are
// emitted TRANSPOSED (WT[n][k], bf16, unpadded 64x64) for MFMA B-operand loads.
__global__ void k_precomp(const float* msg_W, const float* msg_b, const float* upd_W,
                          u16* Wu1T, u16* A1T, u16* A2T, float* C1) {
  int l = blockIdx.x, t = threadIdx.x;
  const float* WmT = msg_W + l * 8192;
  const float* WmB = WmT + 4096;
  const float* Wu1 = upd_W + l * 8192;
  const float* Wu2 = Wu1 + 4096;
  for (int o = t; o < 4096; o += 256) {
    int a = o >> 6, b = o & 63;   // a = k-dim, b = n-dim
    float a1 = 0.f, a2 = 0.f;
    for (int j = 0; j < 64; ++j) {
      float w2 = Wu2[j * 64 + b];
      a1 = fmaf(WmT[a * 64 + j], w2, a1);
      a2 = fmaf(WmB[a * 64 + j], w2, a2);
    }
    A1T[l * 4096 + b * 64 + a]  = (u16)f2bf(a1);
    A2T[l * 4096 + b * 64 + a]  = (u16)f2bf(a2);
    Wu1T[l * 4096 + b * 64 + a] = (u16)f2bf(Wu1[a * 64 + b]);
  }
  if (t < 64) {
    float acc = 0.f;
    for (int j = 0; j < 64; ++j) acc = fmaf(msg_b[l * 64 + j], Wu2[j * 64 + t], acc);
    C1[l * 64 + t] = acc;
  }
}

__global__ void k_trans(const float* Wi, const float* Wf, u16* WiT, u16* WfT) {
  const float* W = blockIdx.x ? Wf : Wi;
  u16* WT = blockIdx.x ? WfT : WiT;
  for (int o = threadIdx.x; o < 4096; o += 256) {
    int k = o >> 6, n = o & 63;
    WT[n * 64 + k] = (u16)f2bf(W[k * 64 + n]);
  }
}

// ============================ MFMA helpers ============================
// Wave w owns rows [w*16, w*16+16). A-frag: A[m=lane&15][k=quad*8+j].
// B-frag: B[k=quad*8+j][n=lane&15] == WT[n][k] rows. C/D: col=lane&15, row=quad*4+reg.
__device__ __forceinline__ void mm4(const u16* lW, int m16, int q,
                                    bf16x8 a0, bf16x8 a1, f32x4 (&acc)[4]) {
  #pragma unroll
  for (int nt = 0; nt < 4; ++nt) {
    const u16* wp = lW + (nt * 16 + m16) * WSTR + q * 8;
    bf16x8 b0 = *(const bf16x8*)(wp);
    bf16x8 b1 = *(const bf16x8*)(wp + 32);
    acc[nt] = __builtin_amdgcn_mfma_f32_16x16x32_bf16(a0, b0, acc[nt], 0, 0, 0);
    acc[nt] = __builtin_amdgcn_mfma_f32_16x16x32_bf16(a1, b1, acc[nt], 0, 0, 0);
  }
}

// stage 64x64 bf16 weight (unpadded global) into padded LDS (stride WSTR)
__device__ __forceinline__ void stage_W(const u16* __restrict__ WT, u16* lW) {
  int t = threadIdx.x;
  int r = t >> 2, seg = (t & 3) * 16;
  const uint4* p = (const uint4*)(WT + r * 64 + seg);
  uint4 a = p[0], b = p[1];
  *(uint4*)(lW + r * WSTR + seg) = a;
  *(uint4*)(lW + r * WSTR + seg + 8) = b;
}

// stage 64-row bf16 H tile into padded LDS
__device__ __forceinline__ void stage_H(const u16* __restrict__ Hin, int R0, u16* lT) {
  int t = threadIdx.x;
  int r = t >> 2, seg = (t & 3) * 16;
  int gr = R0 + r;
  uint4 a = {0, 0, 0, 0}, b = {0, 0, 0, 0};
  if (gr < NN) {
    const uint4* p = (const uint4*)(Hin + (size_t)gr * 64 + seg);
    a = p[0]; b = p[1];
  }
  *(uint4*)(lT + r * WSTR + seg) = a;
  *(uint4*)(lT + r * WSTR + seg + 8) = b;
}

// ============================ input projection ============================
// H[inst] = relu((x + noise_inst) @ Wi + bi), bf16 out
__global__ __launch_bounds__(256) void k_input(const float* __restrict__ x,
                                               const u16* __restrict__ WiT,
                                               const float* __restrict__ bi,
                                               u16* __restrict__ HoutB) {
  __shared__ __align__(16) u16 lT[64 * WSTR];
  __shared__ __align__(16) u16 lW[64 * WSTR];
  __shared__ float lB[64];
  int t = threadIdx.x;
  int R0 = blockIdx.x * 64;
  int inst = blockIdx.y;
  u16* Hout = HoutB + (size_t)inst * SLAB;
  {
    int r = t >> 2, seg = (t & 3) * 16;
    int gr = R0 + r;
    float v[16];
    if (gr < NN) {
      const float4* xp = (const float4*)(x + (size_t)gr * 64 + seg);
      #pragma unroll
      for (int qq = 0; qq < 4; ++qq) {
        float4 f = xp[qq];
        v[qq * 4 + 0] = f.x; v[qq * 4 + 1] = f.y;
        v[qq * 4 + 2] = f.z; v[qq * 4 + 3] = f.w;
      }
      if (inst > 0) {
        int s = inst - 1;
        #pragma unroll
        for (int j = 0; j < 16; ++j) v[j] += noise_val(s, gr, seg + j);
      }
    } else {
      #pragma unroll
      for (int j = 0; j < 16; ++j) v[j] = 0.f;
    }
    uint32_t pk[8];
    #pragma unroll
    for (int j = 0; j < 8; ++j)
      pk[j] = f2bf(v[2 * j]) | (f2bf(v[2 * j + 1]) << 16);
    uint4 A = {pk[0], pk[1], pk[2], pk[3]};
    uint4 B = {pk[4], pk[5], pk[6], pk[7]};
    *(uint4*)(lT + r * WSTR + seg) = A;
    *(uint4*)(lT + r * WSTR + seg + 8) = B;
  }
  stage_W(WiT, lW);
  if (t < 64) lB[t] = bi[t];
  __syncthreads();
  int l = t & 63, w = t >> 6;
  int m16 = l & 15, q = l >> 4;
  const u16* aRow = lT + (w * 16 + m16) * WSTR + q * 8;
  bf16x8 fa0 = *(const bf16x8*)(aRow);
  bf16x8 fa1 = *(const bf16x8*)(aRow + 32);
  f32x4 acc[4] = {{0.f, 0.f, 0.f, 0.f}, {0.f, 0.f, 0.f, 0.f},
                  {0.f, 0.f, 0.f, 0.f}, {0.f, 0.f, 0.f, 0.f}};
  mm4(lW, m16, q, fa0, fa1, acc);
  #pragma unroll
  for (int nt = 0; nt < 4; ++nt) {
    int c = nt * 16 + m16;
    #pragma unroll
    for (int r_ = 0; r_ < 4; ++r_) {
      int row = w * 16 + q * 4 + r_;
      int gr = R0 + row;
      if (gr < NN) {
        float vv = fmaxf(acc[nt][r_] + lB[c], 0.f);
        Hout[(size_t)gr * 64 + c] = (u16)f2bf(vv);
      }
    }
  }
}

// ============================ fused gather + layer update ============================
// Hn = relu(H@Wu1 + g*(H@A1) + (cinv*gatherSum(H))@A2 + b0 + g*c1)
__global__ __launch_bounds__(256) void k_layer(const u16* __restrict__ HinB,
                                               u16* __restrict__ HoutB,
                                               const int* __restrict__ row_ptr,
                                               const int* __restrict__ col,
                                               const int* __restrict__ cnt,
                                               const float* __restrict__ cinv,
                                               const u16* __restrict__ Wu1T,
                                               const u16* __restrict__ A1T,
                                               const u16* __restrict__ A2T,
                                               const float* __restrict__ b0,
                                               const float* __restrict__ c1) {
  __shared__ __align__(16) u16 lT[64 * WSTR];
  __shared__ __align__(16) u16 lS[64 * WSTR];
  __shared__ __align__(16) u16 lW[64 * WSTR];
  __shared__ float lB[128];
  __shared__ float lG[64];
  int t = threadIdx.x;
  int R0 = blockIdx.x * 64;
  const u16* Hin = HinB + (size_t)blockIdx.y * SLAB;
  u16* Hout = HoutB + (size_t)blockIdx.y * SLAB;

  stage_H(Hin, R0, lT);
  stage_W(Wu1T, lW);
  if (t < 64) {
    lB[t] = b0[t];
    lB[64 + t] = c1[t];
    int gr = R0 + t;
    lG[t] = (gr < NN && cnt[gr] > 0) ? 1.f : 0.f;
  }
  // gather bf16 neighbor rows: 16 lanes x 8 B per edge row
  {
    int wv = t >> 6, sub = (t >> 4) & 3, f0 = (t & 15) << 2;
    const u16* hb = Hin + f0;
    #pragma unroll
    for (int b = 0; b < 4; ++b) {
      int r = wv * 16 + b * 4 + sub;
      int n = R0 + r;
      float g0 = 0.f, g1 = 0.f, g2 = 0.f, g3 = 0.f;
      if (n < NN) {
        int e = row_ptr[n], end = row_ptr[n + 1];
        for (; e + 4 <= end; e += 4) {
          uint2 p0 = *(const uint2*)(hb + (size_t)col[e] * 64);
          uint2 p1 = *(const uint2*)(hb + (size_t)col[e + 1] * 64);
          uint2 p2 = *(const uint2*)(hb + (size_t)col[e + 2] * 64);
          uint2 p3 = *(const uint2*)(hb + (size_t)col[e + 3] * 64);
          g0 += (__uint_as_float(p0.x << 16) + __uint_as_float(p1.x << 16)) +
                (__uint_as_float(p2.x << 16) + __uint_as_float(p3.x << 16));
          g1 += (__uint_as_float(p0.x & 0xffff0000u) + __uint_as_float(p1.x & 0xffff0000u)) +
                (__uint_as_float(p2.x & 0xffff0000u) + __uint_as_float(p3.x & 0xffff0000u));
          g2 += (__uint_as_float(p0.y << 16) + __uint_as_float(p1.y << 16)) +
                (__uint_as_float(p2.y << 16) + __uint_as_float(p3.y << 16));
          g3 += (__uint_as_float(p0.y & 0xffff0000u) + __uint_as_float(p1.y & 0xffff0000u)) +
                (__uint_as_float(p2.y & 0xffff0000u) + __uint_as_float(p3.y & 0xffff0000u));
        }
        for (; e < end; ++e) {
          uint2 p0 = *(const uint2*)(hb + (size_t)col[e] * 64);
          g0 += __uint_as_float(p0.x << 16);
          g1 += __uint_as_float(p0.x & 0xffff0000u);
          g2 += __uint_as_float(p0.y << 16);
          g3 += __uint_as_float(p0.y & 0xffff0000u);
        }
        float ci = cinv[n];
        g0 *= ci; g1 *= ci; g2 *= ci; g3 *= ci;
      }
      uint2 pk;
      pk.x = f2bf(g0) | (f2bf(g1) << 16);
      pk.y = f2bf(g2) | (f2bf(g3) << 16);
      *(uint2*)(lS + r * WSTR + f0) = pk;
    }
  }
  __syncthreads();

  int l = t & 63, w = t >> 6;
  int m16 = l & 15, q = l >> 4;
  const u16* aRow = lT + (w * 16 + m16) * WSTR + q * 8;
  bf16x8 fa0 = *(const bf16x8*)(aRow);
  bf16x8 fa1 = *(const bf16x8*)(aRow + 32);
  float gA = lG[w * 16 + m16];
  f32x4 acc[4] = {{0.f, 0.f, 0.f, 0.f}, {0.f, 0.f, 0.f, 0.f},
                  {0.f, 0.f, 0.f, 0.f}, {0.f, 0.f, 0.f, 0.f}};
  mm4(lW, m16, q, fa0, fa1, acc);              // H @ Wu1
  __syncthreads();
  stage_W(A1T, lW);
  __syncthreads();
  bf16x8 zz = {0, 0, 0, 0, 0, 0, 0, 0};
  bf16x8 ga0 = (gA != 0.f) ? fa0 : zz;
  bf16x8 ga1 = (gA != 0.f) ? fa1 : zz;
  mm4(lW, m16, q, ga0, ga1, acc);              // g * (H @ A1)
  __syncthreads();
  stage_W(A2T, lW);
  __syncthreads();
  const u16* sRow = lS + (w * 16 + m16) * WSTR + q * 8;
  bf16x8 fs0 = *(const bf16x8*)(sRow);
  bf16x8 fs1 = *(const bf16x8*)(sRow + 32);
  mm4(lW, m16, q, fs0, fs1, acc);              // (cinv*S) @ A2
  #pragma unroll
  for (int nt = 0; nt < 4; ++nt) {
    int c = nt * 16 + m16;
    #pragma unroll
    for (int r_ = 0; r_ < 4; ++r_) {
      int row = w * 16 + q * 4 + r_;
      int gr = R0 + row;
      if (gr < NN) {
        float vv = acc[nt][r_] + lB[c] + lG[row] * lB[64 + c];
        vv = fmaxf(vv, 0.f);
        Hout[(size_t)gr * 64 + c] = (u16)f2bf(vv);
      }
    }
  }
}

// ============================ final projection ============================
// inst 0 -> out_causal (f32); inst i>=1 -> Z slab i-1 (f32)
__global__ __launch_bounds__(256) void k_final(const u16* __restrict__ HinB,
                                               const u16* __restrict__ WfT,
                                               const float* __restrict__ bfv,
                                               float* __restrict__ outCausal,
                                               float* __restrict__ Z) {
  __shared__ __align__(16) u16 lT[64 * WSTR];
  __shared__ __align__(16) u16 lW[64 * WSTR];
  __shared__ float lB[64];
  int t = threadIdx.x;
  int R0 = blockIdx.x * 64;
  int inst = blockIdx.y;
  const u16* Hin = HinB + (size_t)inst * SLAB;
  stage_H(Hin, R0, lT);
  stage_W(WfT, lW);
  if (t < 64) lB[t] = bfv[t];
  __syncthreads();
  int l = t & 63, w = t >> 6;
  int m16 = l & 15, q = l >> 4;
  const u16* aRow = lT + (w * 16 + m16) * WSTR + q * 8;
  bf16x8 fa0 = *(const bf16x8*)(aRow);
  bf16x8 fa1 = *(const bf16x8*)(aRow + 32);
  f32x4 acc[4] = {{0.f, 0.f, 0.f, 0.f}, {0.f, 0.f, 0.f, 0.f},
                  {0.f, 0.f, 0.f, 0.f}, {0.f, 0.f, 0.f, 0.f}};
  mm4(lW, m16, q, fa0, fa1, acc);
  float* zdst = (inst == 0) ? outCausal : (Z + (size_t)(inst - 1) * SLAB);
  #pragma unroll
  for (int nt = 0; nt < 4; ++nt) {
    int c = nt * 16 + m16;
    #pragma unroll
    for (int r_ = 0; r_ < 4; ++r_) {
      int row = w * 16 + q * 4 + r_;
      int gr = R0 + row;
      if (gr < NN) zdst[(size_t)gr * 64 + c] = acc[nt][r_] + lB[c];
    }
  }
}

// -------- u from 4 z-sample slabs --------
__global__ __launch_bounds__(256) void k_u(const float* __restrict__ Z,
                                           float* __restrict__ u) {
  int n = blockIdx.x * 4 + (threadIdx.x >> 6);
  int lane = threadIdx.x & 63;
  if (n >= NN) return;
  size_t base = (size_t)n * 64 + lane;
  float z0 = Z[base];
  float z1 = Z[SLAB + base];
  float z2 = Z[2 * SLAB + base];
  float z3 = Z[3 * SLAB + base];
  float m = 0.25f * (z0 + z1 + z2 + z3);
  float d0 = z0 - m, d1 = z1 - m, d2 = z2 - m, d3 = z3 - m;
  float v = d0 * d0 + d1 * d1 + d2 * d2 + d3 * d3;
  for (int off = 32; off > 0; off >>= 1) v += __shfl_down(v, off, 64);
  if (lane == 0) u[n] = fmaxf(v * (1.0f / 3.0f), 1e-6f);
}

// ============================ launch ============================
extern "C" void kernel_launch(void* const* d_in, const int* in_sizes, int n_in,
                              void* d_out, int out_size, void* d_ws, size_t ws_size,
                              hipStream_t stream) {
  const float* x      = (const float*)d_in[0];
  const int*   eidx   = (const int*)d_in[1];
  const void*  mask   = d_in[2];
  const float* Wi     = (const float*)d_in[3];
  const float* bi     = (const float*)d_in[4];
  const float* msg_W  = (const float*)d_in[5];
  const float* msg_b  = (const float*)d_in[6];
  const float* upd_W  = (const float*)d_in[7];
  const float* upd_b  = (const float*)d_in[8];
  const float* Wf     = (const float*)d_in[9];
  const float* bfv    = (const float*)d_in[10];

  const int* src = eidx;
  const int* dst = eidx + EE;

  char* ws = (char*)d_ws;
  size_t off = 0;
  auto alloc = [&](size_t bytes) -> void* {
    void* p = ws + off;
    off += (bytes + 255) & ~(size_t)255;
    return p;
  };

  int*   cnt     = (int*)alloc(NN * sizeof(int));
  float* cinv    = (float*)alloc(NN * sizeof(float));
  int*   row_ptr = (int*)alloc((NN + 1) * sizeof(int));
  int*   cursor  = (int*)alloc(NN * sizeof(int));
  int*   col     = (int*)alloc(EE * sizeof(int));
  int*   bsums   = (int*)alloc(128 * sizeof(int));
  int*   mode_p  = (int*)alloc(sizeof(int));
  u16*   Wu1T    = (u16*)alloc(2 * 4096 * sizeof(u16));
  u16*   A1T     = (u16*)alloc(2 * 4096 * sizeof(u16));
  u16*   A2T     = (u16*)alloc(2 * 4096 * sizeof(u16));
  u16*   WiT     = (u16*)alloc(4096 * sizeof(u16));
  u16*   WfT     = (u16*)alloc(4096 * sizeof(u16));
  float* C1      = (float*)alloc(2 * 64 * sizeof(float));
  u16*   HA      = (u16*)alloc(5 * SLAB * sizeof(u16));   // 64 MB
  u16*   HB      = (u16*)alloc(5 * SLAB * sizeof(u16));   // 64 MB
  float* Z       = (float*)alloc(4 * SLAB * sizeof(float)); // 102.4 MB

  float* out_causal = (float*)d_out;
  float* out_u      = (float*)d_out + SLAB;

  // ---- CSR build ----
  k_detect<<<1, 256, 0, stream>>>((const unsigned*)mask, mode_p);
  hipMemsetAsync(cnt, 0, NN * sizeof(int), stream);
  k_count<<<EE / 256, 256, 0, stream>>>(mask, dst, cnt, mode_p);
  const int SCAN_BLKS = (NN + 1023) / 1024;  // 98
  k_scan_a<<<SCAN_BLKS, 256, 0, stream>>>(cnt, bsums);
  k_scan_b<<<1, 128, 0, stream>>>(bsums, SCAN_BLKS, row_ptr + NN);
  k_scan_c<<<SCAN_BLKS, 256, 0, stream>>>(cnt, bsums, row_ptr, cursor, cinv);
  k_fill<<<EE / 256, 256, 0, stream>>>(mask, src, dst, cursor, col, mode_p);

  // ---- weights ----
  k_precomp<<<2, 256, 0, stream>>>(msg_W, msg_b, upd_W, Wu1T, A1T, A2T, C1);
  k_trans<<<2, 256, 0, stream>>>(Wi, Wf, WiT, WfT);

  // ---- 5 batched GNN passes ----
  dim3 g5(GEMM_BX, 5);
  k_input<<<g5, 256, 0, stream>>>(x, WiT, bi, HA);
  k_layer<<<g5, 256, 0, stream>>>(HA, HB, row_ptr, col, cnt, cinv,
                                  Wu1T, A1T, A2T, upd_b, C1);
  k_layer<<<g5, 256, 0, stream>>>(HB, HA, row_ptr, col, cnt, cinv,
                                  Wu1T + 4096, A1T + 4096, A2T + 4096,
                                  upd_b + 64, C1 + 64);
  k_final<<<g5, 256, 0, stream>>>(HA, WfT, bfv, out_causal, Z);
  k_u<<<NN / 4, 256, 0, stream>>>(Z, out_u);

  (void)in_sizes; (void)n_in; (void)out_size; (void)ws_size;
}

// Round 5
// 563.388 us; speedup vs baseline: 2.8200x; 1.1791x over previous
//
#include <hip/hip_runtime.h>
#include <stdint.h>

#define NN 100000
#define EE 800000
#define GEMM_BX 1563          // ceil(100000/64)
#define WSTR 72               // padded bf16 LDS row stride (144 B: 2-way bank aliasing = free)
#define SLAB ((size_t)NN * 64)

typedef unsigned short u16;
typedef __attribute__((ext_vector_type(8))) short bf16x8;   // 8 bf16 = 4 VGPRs
typedef __attribute__((ext_vector_type(4))) float f32x4;

// f32 -> bf16 RNE
__device__ __forceinline__ uint32_t f2bf(float f) {
  uint32_t u = __float_as_uint(f);
  return (u + 0x7fffu + ((u >> 16) & 1u)) >> 16;
}

// ============================ threefry / noise ============================
__device__ __forceinline__ void tf_round(uint32_t& x0, uint32_t& x1, int r) {
  x0 += x1;
  x1 = (x1 << r) | (x1 >> (32 - r));
  x1 ^= x0;
}

// threefry2x32 with key (0, 42) == jax.random.key(42)
__device__ __forceinline__ void threefry_0_42(uint32_t c0, uint32_t c1,
                                              uint32_t& o0, uint32_t& o1) {
  const uint32_t ks0 = 0u, ks1 = 42u, ks2 = 0x1BD11BDAu ^ 42u;
  uint32_t x0 = c0 + ks0, x1 = c1 + ks1;
  tf_round(x0, x1, 13); tf_round(x0, x1, 15); tf_round(x0, x1, 26); tf_round(x0, x1, 6);
  x0 += ks1; x1 += ks2 + 1u;
  tf_round(x0, x1, 17); tf_round(x0, x1, 29); tf_round(x0, x1, 16); tf_round(x0, x1, 24);
  x0 += ks2; x1 += ks0 + 2u;
  tf_round(x0, x1, 13); tf_round(x0, x1, 15); tf_round(x0, x1, 26); tf_round(x0, x1, 6);
  x0 += ks0; x1 += ks1 + 3u;
  tf_round(x0, x1, 17); tf_round(x0, x1, 29); tf_round(x0, x1, 16); tf_round(x0, x1, 24);
  x0 += ks1; x1 += ks2 + 4u;
  tf_round(x0, x1, 13); tf_round(x0, x1, 15); tf_round(x0, x1, 26); tf_round(x0, x1, 6);
  x0 += ks2; x1 += ks0 + 5u;
  o0 = x0; o1 = x1;
}

// jax_threefry_partitionable noise (verified R2): bits = o0^o1 of threefry((0,42),(0,f))
// erfinv: Giles poly; w via hw v_log_f32 (fma keeps 1-u^2 exact); p2 branch
// (0.33%/lane) behind a wave-uniform __any vote — 81% of waves skip it.
__device__ __forceinline__ float noise_val(int s, int n, int d) {
  uint32_t f = (uint32_t)s * 6400000u + (uint32_t)n * 64u + (uint32_t)d;
  uint32_t o0, o1;
  threefry_0_42(0u, f, o0, o1);
  uint32_t bits = o0 ^ o1;
  float v = __uint_as_float((bits >> 9) | 0x3f800000u) - 1.0f;
  const float LO = -0.99999994f;
  float u = v * 2.0f + LO;
  u = fmaxf(u, LO);
  float w = -__logf(fmaf(-u, u, 1.0f));
  float ww = w - 2.5f;
  float p = 2.81022636e-08f;
  p = fmaf(p, ww, 3.43273939e-07f);
  p = fmaf(p, ww, -3.5233877e-06f);
  p = fmaf(p, ww, -4.39150654e-06f);
  p = fmaf(p, ww, 0.00021858087f);
  p = fmaf(p, ww, -0.00125372503f);
  p = fmaf(p, ww, -0.00417768164f);
  p = fmaf(p, ww, 0.246640727f);
  p = fmaf(p, ww, 1.50140941f);
  if (__any(w >= 5.0f)) {
    float ws = sqrtf(w) - 3.0f;
    float p2 = -0.000200214257f;
    p2 = fmaf(p2, ws, 0.000100950558f);
    p2 = fmaf(p2, ws, 0.00134934322f);
    p2 = fmaf(p2, ws, -0.00367342844f);
    p2 = fmaf(p2, ws, 0.00573950773f);
    p2 = fmaf(p2, ws, -0.0076224613f);
    p2 = fmaf(p2, ws, 0.00943887047f);
    p2 = fmaf(p2, ws, 1.00167406f);
    p2 = fmaf(p2, ws, 2.83297682f);
    p = (w < 5.0f) ? p : p2;
  }
  return 0.141421356f * (p * u);   // 0.1 * sqrt(2) * erfinv(u)
}

// ============================ mask dtype detection ============================
__device__ __forceinline__ int mask_at(const void* m, int e, int mode) {
  if (mode == 0) return ((const int*)m)[e] != 0;
  if (mode == 1) return ((const unsigned char*)m)[e] != 0;
  return ((const float*)m)[e] != 0.0f;
}

__global__ void k_detect(const unsigned* mw, int* mode_out) {
  __shared__ int nonbin, nonfloat;
  if (threadIdx.x == 0) { nonbin = 0; nonfloat = 0; }
  __syncthreads();
  int lb = 0, lf = 0;
  for (int i = threadIdx.x; i < 4096; i += 256) {
    unsigned v = mw[i];
    if (v > 1u) lb = 1;
    if (v != 0u && v != 0x3F800000u) lf = 1;
  }
  if (lb) atomicOr(&nonbin, 1);
  if (lf) atomicOr(&nonfloat, 1);
  __syncthreads();
  if (threadIdx.x == 0)
    mode_out[0] = (nonbin == 0) ? 0 : ((nonfloat == 0) ? 2 : 1);
}

// ============================ CSR build ============================
__global__ void k_count(const void* mask, const int* dst, int* cnt, const int* mode_p) {
  int e = blockIdx.x * 256 + threadIdx.x;
  if (e >= EE) return;
  if (mask_at(mask, e, *mode_p)) atomicAdd(&cnt[dst[e]], 1);
}

__global__ void k_scan_a(const int* cnt, int* blockSums) {
  __shared__ int sd[256];
  int t = threadIdx.x;
  int base = blockIdx.x * 1024 + t * 4;
  int s = 0;
  #pragma unroll
  for (int j = 0; j < 4; ++j) {
    int i = base + j;
    if (i < NN) s += cnt[i];
  }
  sd[t] = s;
  __syncthreads();
  for (int off = 128; off > 0; off >>= 1) {
    if (t < off) sd[t] += sd[t + off];
    __syncthreads();
  }
  if (t == 0) blockSums[blockIdx.x] = sd[0];
}

__global__ void k_scan_b(int* blockSums, int nb, int* total_out) {
  __shared__ int sd[128];
  int t = threadIdx.x;
  int v = (t < nb) ? blockSums[t] : 0;
  sd[t] = v;
  __syncthreads();
  for (int off = 1; off < 128; off <<= 1) {
    int x = (t >= off) ? sd[t - off] : 0;
    __syncthreads();
    sd[t] += x;
    __syncthreads();
  }
  if (t < nb) blockSums[t] = sd[t] - v;
  if (t == 0) total_out[0] = sd[127];
}

__global__ void k_scan_c(const int* cnt, const int* blockOffs, int* row_ptr,
                         int* cursor, float* cinv) {
  __shared__ int sd[256];
  int t = threadIdx.x;
  int base = blockIdx.x * 1024 + t * 4;
  int v[4], s = 0;
  #pragma unroll
  for (int j = 0; j < 4; ++j) {
    int i = base + j;
    v[j] = (i < NN) ? cnt[i] : 0;
    s += v[j];
  }
  sd[t] = s;
  __syncthreads();
  for (int off = 1; off < 256; off <<= 1) {
    int x = (t >= off) ? sd[t - off] : 0;
    __syncthreads();
    sd[t] += x;
    __syncthreads();
  }
  int excl = sd[t] - s + blockOffs[blockIdx.x];
  #pragma unroll
  for (int j = 0; j < 4; ++j) {
    int i = base + j;
    if (i < NN) {
      row_ptr[i] = excl;
      cursor[i] = excl;
      cinv[i] = 1.0f / fmaxf((float)v[j], 1.0f);
    }
    excl += v[j];
  }
}

__global__ void k_fill(const void* mask, const int* src, const int* dst,
                       int* cursor, int* col, const int* mode_p) {
  int e = blockIdx.x * 256 + threadIdx.x;
  if (e >= EE) return;
  if (mask_at(mask, e, *mode_p)) {
    int p = atomicAdd(&cursor[dst[e]], 1);
    col[p] = src[e];
  }
}

// ============================ folded / transposed weights (bf16) ============================
// Per layer: A1 = WmT@Wu2, A2 = WmB@Wu2, C1 = msg_b@Wu2. All weight matrices are
// emitted TRANSPOSED (WT[n][k], bf16, unpadded 64x64) for MFMA B-operand loads.
__global__ void k_precomp(const float* msg_W, const float* msg_b, const float* upd_W,
                          u16* Wu1T, u16* A1T, u16* A2T, float* C1) {
  int l = blockIdx.x, t = threadIdx.x;
  const float* WmT = msg_W + l * 8192;
  const float* WmB = WmT + 4096;
  const float* Wu1 = upd_W + l * 8192;
  const float* Wu2 = Wu1 + 4096;
  for (int o = t; o < 4096; o += 256) {
    int a = o >> 6, b = o & 63;   // a = k-dim, b = n-dim
    float a1 = 0.f, a2 = 0.f;
    for (int j = 0; j < 64; ++j) {
      float w2 = Wu2[j * 64 + b];
      a1 = fmaf(WmT[a * 64 + j], w2, a1);
      a2 = fmaf(WmB[a * 64 + j], w2, a2);
    }
    A1T[l * 4096 + b * 64 + a]  = (u16)f2bf(a1);
    A2T[l * 4096 + b * 64 + a]  = (u16)f2bf(a2);
    Wu1T[l * 4096 + b * 64 + a] = (u16)f2bf(Wu1[a * 64 + b]);
  }
  if (t < 64) {
    float acc = 0.f;
    for (int j = 0; j < 64; ++j) acc = fmaf(msg_b[l * 64 + j], Wu2[j * 64 + t], acc);
    C1[l * 64 + t] = acc;
  }
}

__global__ void k_trans(const float* Wi, const float* Wf, u16* WiT, u16* WfT) {
  const float* W = blockIdx.x ? Wf : Wi;
  u16* WT = blockIdx.x ? WfT : WiT;
  for (int o = threadIdx.x; o < 4096; o += 256) {
    int k = o >> 6, n = o & 63;
    WT[n * 64 + k] = (u16)f2bf(W[k * 64 + n]);
  }
}

// ============================ MFMA helpers ============================
// Wave w owns rows [w*16, w*16+16). A-frag: A[m=lane&15][k=quad*8+j].
// B-frag: B[k=quad*8+j][n=lane&15] == WT[n][k] rows. C/D: col=lane&15, row=quad*4+reg.
__device__ __forceinline__ void mm4(const u16* lW, int m16, int q,
                                    bf16x8 a0, bf16x8 a1, f32x4 (&acc)[4]) {
  #pragma unroll
  for (int nt = 0; nt < 4; ++nt) {
    const u16* wp = lW + (nt * 16 + m16) * WSTR + q * 8;
    bf16x8 b0 = *(const bf16x8*)(wp);
    bf16x8 b1 = *(const bf16x8*)(wp + 32);
    acc[nt] = __builtin_amdgcn_mfma_f32_16x16x32_bf16(a0, b0, acc[nt], 0, 0, 0);
    acc[nt] = __builtin_amdgcn_mfma_f32_16x16x32_bf16(a1, b1, acc[nt], 0, 0, 0);
  }
}

// stage 64x64 bf16 weight (unpadded global) into padded LDS (stride WSTR)
__device__ __forceinline__ void stage_W(const u16* __restrict__ WT, u16* lW) {
  int t = threadIdx.x;
  int r = t >> 2, seg = (t & 3) * 16;
  const uint4* p = (const uint4*)(WT + r * 64 + seg);
  uint4 a = p[0], b = p[1];
  *(uint4*)(lW + r * WSTR + seg) = a;
  *(uint4*)(lW + r * WSTR + seg + 8) = b;
}

// stage 64-row bf16 H tile into padded LDS
__device__ __forceinline__ void stage_H(const u16* __restrict__ Hin, int R0, u16* lT) {
  int t = threadIdx.x;
  int r = t >> 2, seg = (t & 3) * 16;
  int gr = R0 + r;
  uint4 a = {0, 0, 0, 0}, b = {0, 0, 0, 0};
  if (gr < NN) {
    const uint4* p = (const uint4*)(Hin + (size_t)gr * 64 + seg);
    a = p[0]; b = p[1];
  }
  *(uint4*)(lT + r * WSTR + seg) = a;
  *(uint4*)(lT + r * WSTR + seg + 8) = b;
}

// ============================ input projection ============================
// H[inst] = relu((x + noise_inst) @ Wi + bi), bf16 out
__global__ __launch_bounds__(256) void k_input(const float* __restrict__ x,
                                               const u16* __restrict__ WiT,
                                               const float* __restrict__ bi,
                                               u16* __restrict__ HoutB) {
  __shared__ __align__(16) u16 lT[64 * WSTR];
  __shared__ __align__(16) u16 lW[64 * WSTR];
  __shared__ float lB[64];
  int t = threadIdx.x;
  int R0 = blockIdx.x * 64;
  int inst = blockIdx.y;
  u16* Hout = HoutB + (size_t)inst * SLAB;
  {
    int r = t >> 2, seg = (t & 3) * 16;
    int gr = R0 + r;
    float v[16];
    if (gr < NN) {
      const float4* xp = (const float4*)(x + (size_t)gr * 64 + seg);
      #pragma unroll
      for (int qq = 0; qq < 4; ++qq) {
        float4 f = xp[qq];
        v[qq * 4 + 0] = f.x; v[qq * 4 + 1] = f.y;
        v[qq * 4 + 2] = f.z; v[qq * 4 + 3] = f.w;
      }
      if (inst > 0) {
        int s = inst - 1;
        #pragma unroll
        for (int j = 0; j < 16; ++j) v[j] += noise_val(s, gr, seg + j);
      }
    } else {
      #pragma unroll
      for (int j = 0; j < 16; ++j) v[j] = 0.f;
    }
    uint32_t pk[8];
    #pragma unroll
    for (int j = 0; j < 8; ++j)
      pk[j] = f2bf(v[2 * j]) | (f2bf(v[2 * j + 1]) << 16);
    uint4 A = {pk[0], pk[1], pk[2], pk[3]};
    uint4 B = {pk[4], pk[5], pk[6], pk[7]};
    *(uint4*)(lT + r * WSTR + seg) = A;
    *(uint4*)(lT + r * WSTR + seg + 8) = B;
  }
  stage_W(WiT, lW);
  if (t < 64) lB[t] = bi[t];
  __syncthreads();
  int l = t & 63, w = t >> 6;
  int m16 = l & 15, q = l >> 4;
  const u16* aRow = lT + (w * 16 + m16) * WSTR + q * 8;
  bf16x8 fa0 = *(const bf16x8*)(aRow);
  bf16x8 fa1 = *(const bf16x8*)(aRow + 32);
  f32x4 acc[4] = {{0.f, 0.f, 0.f, 0.f}, {0.f, 0.f, 0.f, 0.f},
                  {0.f, 0.f, 0.f, 0.f}, {0.f, 0.f, 0.f, 0.f}};
  mm4(lW, m16, q, fa0, fa1, acc);
  #pragma unroll
  for (int nt = 0; nt < 4; ++nt) {
    int c = nt * 16 + m16;
    #pragma unroll
    for (int r_ = 0; r_ < 4; ++r_) {
      int row = w * 16 + q * 4 + r_;
      int gr = R0 + row;
      if (gr < NN) {
        float vv = fmaxf(acc[nt][r_] + lB[c], 0.f);
        Hout[(size_t)gr * 64 + c] = (u16)f2bf(vv);
      }
    }
  }
}

// ============================ fused gather + layer update ============================
// Hn = relu(H@Wu1 + g*(H@A1) + (cinv*gatherSum(H))@A2 + b0 + g*c1)
__global__ __launch_bounds__(256) void k_layer(const u16* __restrict__ HinB,
                                               u16* __restrict__ HoutB,
                                               const int* __restrict__ row_ptr,
                                               const int* __restrict__ col,
                                               const int* __restrict__ cnt,
                                               const float* __restrict__ cinv,
                                               const u16* __restrict__ Wu1T,
                                               const u16* __restrict__ A1T,
                                               const u16* __restrict__ A2T,
                                               const float* __restrict__ b0,
                                               const float* __restrict__ c1) {
  __shared__ __align__(16) u16 lT[64 * WSTR];
  __shared__ __align__(16) u16 lS[64 * WSTR];
  __shared__ __align__(16) u16 lW[64 * WSTR];
  __shared__ float lB[128];
  __shared__ float lG[64];
  int t = threadIdx.x;
  int R0 = blockIdx.x * 64;
  const u16* Hin = HinB + (size_t)blockIdx.y * SLAB;
  u16* Hout = HoutB + (size_t)blockIdx.y * SLAB;

  stage_H(Hin, R0, lT);
  stage_W(Wu1T, lW);
  if (t < 64) {
    lB[t] = b0[t];
    lB[64 + t] = c1[t];
    int gr = R0 + t;
    lG[t] = (gr < NN && cnt[gr] > 0) ? 1.f : 0.f;
  }
  // gather bf16 neighbor rows: 16 lanes x 8 B per edge row
  {
    int wv = t >> 6, sub = (t >> 4) & 3, f0 = (t & 15) << 2;
    const u16* hb = Hin + f0;
    #pragma unroll
    for (int b = 0; b < 4; ++b) {
      int r = wv * 16 + b * 4 + sub;
      int n = R0 + r;
      float g0 = 0.f, g1 = 0.f, g2 = 0.f, g3 = 0.f;
      if (n < NN) {
        int e = row_ptr[n], end = row_ptr[n + 1];
        for (; e + 4 <= end; e += 4) {
          uint2 p0 = *(const uint2*)(hb + (size_t)col[e] * 64);
          uint2 p1 = *(const uint2*)(hb + (size_t)col[e + 1] * 64);
          uint2 p2 = *(const uint2*)(hb + (size_t)col[e + 2] * 64);
          uint2 p3 = *(const uint2*)(hb + (size_t)col[e + 3] * 64);
          g0 += (__uint_as_float(p0.x << 16) + __uint_as_float(p1.x << 16)) +
                (__uint_as_float(p2.x << 16) + __uint_as_float(p3.x << 16));
          g1 += (__uint_as_float(p0.x & 0xffff0000u) + __uint_as_float(p1.x & 0xffff0000u)) +
                (__uint_as_float(p2.x & 0xffff0000u) + __uint_as_float(p3.x & 0xffff0000u));
          g2 += (__uint_as_float(p0.y << 16) + __uint_as_float(p1.y << 16)) +
                (__uint_as_float(p2.y << 16) + __uint_as_float(p3.y << 16));
          g3 += (__uint_as_float(p0.y & 0xffff0000u) + __uint_as_float(p1.y & 0xffff0000u)) +
                (__uint_as_float(p2.y & 0xffff0000u) + __uint_as_float(p3.y & 0xffff0000u));
        }
        for (; e < end; ++e) {
          uint2 p0 = *(const uint2*)(hb + (size_t)col[e] * 64);
          g0 += __uint_as_float(p0.x << 16);
          g1 += __uint_as_float(p0.x & 0xffff0000u);
          g2 += __uint_as_float(p0.y << 16);
          g3 += __uint_as_float(p0.y & 0xffff0000u);
        }
        float ci = cinv[n];
        g0 *= ci; g1 *= ci; g2 *= ci; g3 *= ci;
      }
      uint2 pk;
      pk.x = f2bf(g0) | (f2bf(g1) << 16);
      pk.y = f2bf(g2) | (f2bf(g3) << 16);
      *(uint2*)(lS + r * WSTR + f0) = pk;
    }
  }
  __syncthreads();

  int l = t & 63, w = t >> 6;
  int m16 = l & 15, q = l >> 4;
  const u16* aRow = lT + (w * 16 + m16) * WSTR + q * 8;
  bf16x8 fa0 = *(const bf16x8*)(aRow);
  bf16x8 fa1 = *(const bf16x8*)(aRow + 32);
  float gA = lG[w * 16 + m16];
  f32x4 acc[4] = {{0.f, 0.f, 0.f, 0.f}, {0.f, 0.f, 0.f, 0.f},
                  {0.f, 0.f, 0.f, 0.f}, {0.f, 0.f, 0.f, 0.f}};
  mm4(lW, m16, q, fa0, fa1, acc);              // H @ Wu1
  __syncthreads();
  stage_W(A1T, lW);
  __syncthreads();
  bf16x8 zz = {0, 0, 0, 0, 0, 0, 0, 0};
  bf16x8 ga0 = (gA != 0.f) ? fa0 : zz;
  bf16x8 ga1 = (gA != 0.f) ? fa1 : zz;
  mm4(lW, m16, q, ga0, ga1, acc);              // g * (H @ A1)
  __syncthreads();
  stage_W(A2T, lW);
  __syncthreads();
  const u16* sRow = lS + (w * 16 + m16) * WSTR + q * 8;
  bf16x8 fs0 = *(const bf16x8*)(sRow);
  bf16x8 fs1 = *(const bf16x8*)(sRow + 32);
  mm4(lW, m16, q, fs0, fs1, acc);              // (cinv*S) @ A2
  #pragma unroll
  for (int nt = 0; nt < 4; ++nt) {
    int c = nt * 16 + m16;
    #pragma unroll
    for (int r_ = 0; r_ < 4; ++r_) {
      int row = w * 16 + q * 4 + r_;
      int gr = R0 + row;
      if (gr < NN) {
        float vv = acc[nt][r_] + lB[c] + lG[row] * lB[64 + c];
        vv = fmaxf(vv, 0.f);
        Hout[(size_t)gr * 64 + c] = (u16)f2bf(vv);
      }
    }
  }
}

// ============================ final projection + variance (fused) ============================
// One block per 64-row tile; iterates all 5 instances: inst 0 -> out_causal,
// inst 1..4 accumulate s1/s2 in registers; per-row variance reduced via
// shfl_xor across the 16-lane quad; writes u directly. No Z buffer.
__global__ __launch_bounds__(256) void k_final(const u16* __restrict__ HinB,
                                               const u16* __restrict__ WfT,
                                               const float* __restrict__ bfv,
                                               float* __restrict__ outCausal,
                                               float* __restrict__ out_u) {
  __shared__ __align__(16) u16 lT[64 * WSTR];
  __shared__ __align__(16) u16 lW[64 * WSTR];
  __shared__ float lB[64];
  int t = threadIdx.x;
  int R0 = blockIdx.x * 64;
  stage_W(WfT, lW);
  if (t < 64) lB[t] = bfv[t];
  int l = t & 63, w = t >> 6;
  int m16 = l & 15, q = l >> 4;
  float s1[16], s2[16];
  #pragma unroll
  for (int j = 0; j < 16; ++j) { s1[j] = 0.f; s2[j] = 0.f; }

  for (int inst = 0; inst < 5; ++inst) {
    __syncthreads();                     // prev reads done / lW+lB visible
    stage_H(HinB + (size_t)inst * SLAB, R0, lT);
    __syncthreads();
    const u16* aRow = lT + (w * 16 + m16) * WSTR + q * 8;
    bf16x8 fa0 = *(const bf16x8*)(aRow);
    bf16x8 fa1 = *(const bf16x8*)(aRow + 32);
    f32x4 acc[4] = {{0.f, 0.f, 0.f, 0.f}, {0.f, 0.f, 0.f, 0.f},
                    {0.f, 0.f, 0.f, 0.f}, {0.f, 0.f, 0.f, 0.f}};
    mm4(lW, m16, q, fa0, fa1, acc);
    #pragma unroll
    for (int nt = 0; nt < 4; ++nt) {
      int c = nt * 16 + m16;
      #pragma unroll
      for (int r_ = 0; r_ < 4; ++r_) {
        float z = acc[nt][r_] + lB[c];
        if (inst == 0) {
          int gr = R0 + w * 16 + q * 4 + r_;
          if (gr < NN) outCausal[(size_t)gr * 64 + c] = z;
        } else {
          s1[nt * 4 + r_] += z;
          s2[nt * 4 + r_] = fmaf(z, z, s2[nt * 4 + r_]);
        }
      }
    }
  }
  // per-row variance: sum over 4 nt in-thread, then over the 16-lane quad
  #pragma unroll
  for (int r_ = 0; r_ < 4; ++r_) {
    float pr = 0.f;
    #pragma unroll
    for (int nt = 0; nt < 4; ++nt) {
      float a = s1[nt * 4 + r_];
      pr += s2[nt * 4 + r_] - 0.25f * a * a;
    }
    #pragma unroll
    for (int msk = 1; msk < 16; msk <<= 1)
      pr += __shfl_xor(pr, msk, 64);
    if (m16 == 0) {
      int gr = R0 + w * 16 + q * 4 + r_;
      if (gr < NN) out_u[gr] = fmaxf(pr * (1.0f / 3.0f), 1e-6f);
    }
  }
}

// ============================ launch ============================
extern "C" void kernel_launch(void* const* d_in, const int* in_sizes, int n_in,
                              void* d_out, int out_size, void* d_ws, size_t ws_size,
                              hipStream_t stream) {
  const float* x      = (const float*)d_in[0];
  const int*   eidx   = (const int*)d_in[1];
  const void*  mask   = d_in[2];
  const float* Wi     = (const float*)d_in[3];
  const float* bi     = (const float*)d_in[4];
  const float* msg_W  = (const float*)d_in[5];
  const float* msg_b  = (const float*)d_in[6];
  const float* upd_W  = (const float*)d_in[7];
  const float* upd_b  = (const float*)d_in[8];
  const float* Wf     = (const float*)d_in[9];
  const float* bfv    = (const float*)d_in[10];

  const int* src = eidx;
  const int* dst = eidx + EE;

  char* ws = (char*)d_ws;
  size_t off = 0;
  auto alloc = [&](size_t bytes) -> void* {
    void* p = ws + off;
    off += (bytes + 255) & ~(size_t)255;
    return p;
  };

  int*   cnt     = (int*)alloc(NN * sizeof(int));
  float* cinv    = (float*)alloc(NN * sizeof(float));
  int*   row_ptr = (int*)alloc((NN + 1) * sizeof(int));
  int*   cursor  = (int*)alloc(NN * sizeof(int));
  int*   col     = (int*)alloc(EE * sizeof(int));
  int*   bsums   = (int*)alloc(128 * sizeof(int));
  int*   mode_p  = (int*)alloc(sizeof(int));
  u16*   Wu1T    = (u16*)alloc(2 * 4096 * sizeof(u16));
  u16*   A1T     = (u16*)alloc(2 * 4096 * sizeof(u16));
  u16*   A2T     = (u16*)alloc(2 * 4096 * sizeof(u16));
  u16*   WiT     = (u16*)alloc(4096 * sizeof(u16));
  u16*   WfT     = (u16*)alloc(4096 * sizeof(u16));
  float* C1      = (float*)alloc(2 * 64 * sizeof(float));
  u16*   HA      = (u16*)alloc(5 * SLAB * sizeof(u16));   // 64 MB
  u16*   HB      = (u16*)alloc(5 * SLAB * sizeof(u16));   // 64 MB

  float* out_causal = (float*)d_out;
  float* out_u      = (float*)d_out + SLAB;

  // ---- CSR build ----
  k_detect<<<1, 256, 0, stream>>>((const unsigned*)mask, mode_p);
  hipMemsetAsync(cnt, 0, NN * sizeof(int), stream);
  k_count<<<EE / 256, 256, 0, stream>>>(mask, dst, cnt, mode_p);
  const int SCAN_BLKS = (NN + 1023) / 1024;  // 98
  k_scan_a<<<SCAN_BLKS, 256, 0, stream>>>(cnt, bsums);
  k_scan_b<<<1, 128, 0, stream>>>(bsums, SCAN_BLKS, row_ptr + NN);
  k_scan_c<<<SCAN_BLKS, 256, 0, stream>>>(cnt, bsums, row_ptr, cursor, cinv);
  k_fill<<<EE / 256, 256, 0, stream>>>(mask, src, dst, cursor, col, mode_p);

  // ---- weights ----
  k_precomp<<<2, 256, 0, stream>>>(msg_W, msg_b, upd_W, Wu1T, A1T, A2T, C1);
  k_trans<<<2, 256, 0, stream>>>(Wi, Wf, WiT, WfT);

  // ---- 5 batched GNN passes ----
  dim3 g5(GEMM_BX, 5);
  k_input<<<g5, 256, 0, stream>>>(x, WiT, bi, HA);
  k_layer<<<g5, 256, 0, stream>>>(HA, HB, row_ptr, col, cnt, cinv,
                                  Wu1T, A1T, A2T, upd_b, C1);
  k_layer<<<g5, 256, 0, stream>>>(HB, HA, row_ptr, col, cnt, cinv,
                                  Wu1T + 4096, A1T + 4096, A2T + 4096,
                                  upd_b + 64, C1 + 64);
  k_final<<<GEMM_BX, 256, 0, stream>>>(HA, WfT, bfv, out_causal, out_u);

  (void)in_sizes; (void)n_in; (void)out_size; (void)ws_size;
}